// Round 6
// baseline (450.794 us; speedup 1.0000x reference)
//
#include <hip/hip_runtime.h>
#include <cstddef>

// Problem constants (from reference)
constexpr int cB = 4, cS = 128, cD = 512, cH = 8, cDK = 64, cF = 2048, cL = 2, cV = 32000;
constexpr int cN = cB * cS; // 512

typedef __attribute__((ext_vector_type(8)))  short short8;  // 8 x bf16 (MFMA frag)
typedef __attribute__((ext_vector_type(4)))  float f32x4;
typedef __attribute__((ext_vector_type(16))) float f32x16;  // 32x32 MFMA acc

__device__ __forceinline__ short f2bf(float x) {            // RNE fp32->bf16
    unsigned u = __builtin_bit_cast(unsigned, x);
    unsigned r = (u + 0x7fffu + ((u >> 16) & 1u)) >> 16;
    return (short)r;
}

// ---------------------------------------------------------------------------
// Embedding + positional encoding (fp32 residual stream)
// ---------------------------------------------------------------------------
__global__ __launch_bounds__(256) void embed_k(const float* __restrict__ emb,
                                               const int* __restrict__ tok,
                                               float* __restrict__ X)
{
    int n = blockIdx.x;
    int tid = threadIdx.x;
    int t = tok[n];
    int pos = n & (cS - 1);
    const float scale = 22.62741699796952f; // sqrt(512)
    for (int d = tid; d < cD; d += 256) {
        int i2 = d & ~1;
        float div = expf(-9.210340371976184f * (float)i2 / (float)cD);
        float arg = (float)pos * div;
        float p = (d & 1) ? cosf(arg) : sinf(arg);
        X[(long)n * cD + d] = emb[(long)t * cD + d] * scale + p;
    }
}

// ---------------------------------------------------------------------------
// LayerNorm -> bf16 (used once, before the generator GEMM)
// ---------------------------------------------------------------------------
__global__ __launch_bounds__(256) void ln_k(const float* __restrict__ X,
                                            const float* __restrict__ g,
                                            const float* __restrict__ bta,
                                            short* __restrict__ Yb)
{
    __shared__ float red[256];
    int row = blockIdx.x, tid = threadIdx.x;
    const float* x = X + (long)row * cD;
    float v0 = x[tid], v1 = x[tid + 256];

    red[tid] = v0 + v1;
    __syncthreads();
    for (int st = 128; st > 0; st >>= 1) { if (tid < st) red[tid] += red[tid + st]; __syncthreads(); }
    float mu = red[0] * (1.0f / (float)cD);
    __syncthreads();

    float d0 = v0 - mu, d1 = v1 - mu;
    red[tid] = d0 * d0 + d1 * d1;
    __syncthreads();
    for (int st = 128; st > 0; st >>= 1) { if (tid < st) red[tid] += red[tid + st]; __syncthreads(); }
    float var = red[0] * (1.0f / (float)cD);
    float rs = rsqrtf(var + 1e-5f);

    Yb[(long)row * cD + tid]       = f2bf(g[tid]       * d0 * rs + bta[tid]);
    Yb[(long)row * cD + tid + 256] = f2bf(g[tid + 256] * d1 * rs + bta[tid + 256]);
}

// ---------------------------------------------------------------------------
// Batched transpose-convert: z slices fp32 [K][N] -> bf16 [N][K] contiguous.
// ---------------------------------------------------------------------------
struct TCP { const float* s[24]; };

__global__ __launch_bounds__(256) void tconv_k(TCP ptrs, short* __restrict__ dst,
                                               int K, int N)
{
    __shared__ float t[64][65];
    const float* s = ptrs.s[blockIdx.z];
    short* d = dst + (long)blockIdx.z * K * N;
    int k0 = blockIdx.y * 64, n0 = blockIdx.x * 64;
    int tid = threadIdx.x;
    const f32x4* s4 = (const f32x4*)s;
#pragma unroll
    for (int i = 0; i < 4; i++) {
        int lin = tid + i * 256;
        int r = lin >> 4, c4 = lin & 15;
        f32x4 v = s4[(long)(k0 + r) * (N >> 2) + (n0 >> 2) + c4];
        t[r][c4 * 4 + 0] = v[0]; t[r][c4 * 4 + 1] = v[1];
        t[r][c4 * 4 + 2] = v[2]; t[r][c4 * 4 + 3] = v[3];
    }
    __syncthreads();
#pragma unroll
    for (int i = 0; i < 2; i++) {
        int lin = tid + i * 256;
        int r = lin >> 3, c8 = lin & 7;
        short8 o;
#pragma unroll
        for (int j = 0; j < 8; j++) o[j] = f2bf(t[c8 * 8 + j][r]);
        *(short8*)&d[(long)(n0 + r) * K + k0 + c8 * 8] = o;
    }
}

// ---------------------------------------------------------------------------
// 8-wave split-K bf16 MFMA GEMM.  C = act(LN?(A) @ B + bias) + res
// 512 threads = 8 waves: wave-group grp = wid>>2 owns one K-half; quad 2x2
// tiles the (MR*32)x(NR*32) block output. Combined [BM][128] tile per step
// (cols 0-63 = half0 chunk, 64-127 = half1 chunk) -> steps = K/128.
// End: group-1 acc added to group-0 via LDS, group-0 does epilogue.
// ---------------------------------------------------------------------------
template <int MR, int NR, bool LNF>
__global__ __launch_bounds__(512) void gemm8_k(
    const short* __restrict__ Abf, const float* __restrict__ Af,
    const float* __restrict__ lng, const float* __restrict__ lnb,
    const short* __restrict__ Bt,
    const float* __restrict__ bias, const float* __restrict__ res,
    float* __restrict__ C, short* __restrict__ Cb,
    int N, int K, int relu, long btStride, long cStride)
{
    constexpr int BM = MR * 32, BN = NR * 32, PITCH = 136; // 128 + 8
    constexpr int ACH = (BM * 128) / (8 * 512);
    constexpr int BCH = (BN * 128) / (8 * 512);
    static_assert(ACH >= 1 && BCH >= 1, "tile too small");
    __shared__ short As[2][BM * PITCH];
    __shared__ short Bs[2][BN * PITCH];
    __shared__ float red[4][64][MR * NR * 4];
    __shared__ float mu_s[BM], rs_s[BM];
    __shared__ float gb_s[2][LNF ? 512 : 8];

    const short* Bm = Bt + (long)blockIdx.z * btStride;
    int tid = threadIdx.x;
    int lane = tid & 63, wid = tid >> 6;
    int grp = wid >> 2, quad = wid & 3;
    int wr = quad >> 1, wc = quad & 1;
    int m0 = blockIdx.y * BM, n0 = blockIdx.x * BN;
    int lrow = lane & 15, koff = (lane >> 4) * 8;
    const int Kh = K >> 1;

    if constexpr (LNF) {   // per-row LN stats over K (==512 at LNF sites)
        constexpr int TPR = 512 / BM;
        int r = tid / TPR, sub = tid % TPR;
        const f32x4* row4 = (const f32x4*)(Af + (long)(m0 + r) * K);
        float s = 0.f, s2 = 0.f;
        for (int i = sub; i < (K >> 2); i += TPR) {
            f32x4 v = row4[i];
            s  += v[0] + v[1] + v[2] + v[3];
            s2 += v[0] * v[0] + v[1] * v[1] + v[2] * v[2] + v[3] * v[3];
        }
#pragma unroll
        for (int o = TPR >> 1; o > 0; o >>= 1) {
            s += __shfl_xor(s, o); s2 += __shfl_xor(s2, o);
        }
        if (sub == 0) {
            float mu = s / (float)K;
            float var = s2 / (float)K - mu * mu;
            mu_s[r] = mu; rs_s[r] = rsqrtf(var + 1e-5f);
        }
        for (int i = tid; i < 512; i += 512) { gb_s[0][i] = lng[i]; gb_s[1][i] = lnb[i]; }
        __syncthreads();
    }

    f32x4 acc[MR][NR];
#pragma unroll
    for (int m = 0; m < MR; m++)
#pragma unroll
        for (int n = 0; n < NR; n++) acc[m][n] = f32x4{0.f, 0.f, 0.f, 0.f};

    short8 qa0[ACH], qa1[ACH], qb0[BCH], qb1[BCH];

    auto stage = [&](int step, short8 (&qa)[ACH], short8 (&qb)[BCH]) {
#pragma unroll
        for (int i = 0; i < ACH; i++) {
            int lin = tid + i * 512, r = lin >> 4, c8 = lin & 15;
            int kg = (c8 < 8) ? (step * 64 + c8 * 8) : (Kh + step * 64 + (c8 - 8) * 8);
            if constexpr (LNF) {
                const f32x4* p = (const f32x4*)(Af + (long)(m0 + r) * K + kg);
                f32x4 f0 = p[0], f1 = p[1];
                float mu = mu_s[r], rs = rs_s[r];
                short8 o;
#pragma unroll
                for (int j = 0; j < 4; j++)
                    o[j] = f2bf((f0[j] - mu) * rs * gb_s[0][kg + j] + gb_s[1][kg + j]);
#pragma unroll
                for (int j = 0; j < 4; j++)
                    o[4 + j] = f2bf((f1[j] - mu) * rs * gb_s[0][kg + 4 + j] + gb_s[1][kg + 4 + j]);
                qa[i] = o;
            } else {
                qa[i] = *(const short8*)&Abf[(long)(m0 + r) * K + kg];
            }
        }
#pragma unroll
        for (int i = 0; i < BCH; i++) {
            int lin = tid + i * 512, r = lin >> 4, c8 = lin & 15;
            int kg = (c8 < 8) ? (step * 64 + c8 * 8) : (Kh + step * 64 + (c8 - 8) * 8);
            qb[i] = *(const short8*)&Bm[(long)(n0 + r) * K + kg];
        }
    };
    auto writeT = [&](int buf, short8 (&qa)[ACH], short8 (&qb)[BCH]) {
#pragma unroll
        for (int i = 0; i < ACH; i++) {
            int lin = tid + i * 512, r = lin >> 4, c8 = lin & 15;
            *(short8*)&As[buf][r * PITCH + c8 * 8] = qa[i];
        }
#pragma unroll
        for (int i = 0; i < BCH; i++) {
            int lin = tid + i * 512, r = lin >> 4, c8 = lin & 15;
            *(short8*)&Bs[buf][r * PITCH + c8 * 8] = qb[i];
        }
    };
    auto mfmaStep = [&](int buf) {
#pragma unroll
        for (int kk2 = 0; kk2 < 2; kk2++) {
            int kk = grp * 64 + kk2 * 32;
            short8 a[MR], b[NR];
#pragma unroll
            for (int m = 0; m < MR; m++)
                a[m] = *(const short8*)&As[buf][(wr * MR * 16 + m * 16 + lrow) * PITCH + kk + koff];
#pragma unroll
            for (int n = 0; n < NR; n++)
                b[n] = *(const short8*)&Bs[buf][(wc * NR * 16 + n * 16 + lrow) * PITCH + kk + koff];
#pragma unroll
            for (int m = 0; m < MR; m++)
#pragma unroll
                for (int n = 0; n < NR; n++)
                    acc[m][n] = __builtin_amdgcn_mfma_f32_16x16x32_bf16(a[m], b[n], acc[m][n], 0, 0, 0);
        }
    };

    const int steps = K >> 7;   // K / 128
    stage(0, qa0, qb0);
    if (steps > 1) stage(1, qa1, qb1);

    int st = 0;
    for (;;) {
        writeT(0, qa0, qb0);
        __syncthreads();
        if (st + 2 < steps) stage(st + 2, qa0, qb0);
        mfmaStep(0);
        st++; if (st >= steps) break;

        writeT(1, qa1, qb1);
        __syncthreads();
        if (st + 2 < steps) stage(st + 2, qa1, qb1);
        mfmaStep(1);
        st++; if (st >= steps) break;
    }

    // cross-group reduction: grp1 -> LDS, grp0 adds + epilogue
    __syncthreads();
    if (grp == 1) {
#pragma unroll
        for (int m = 0; m < MR; m++)
#pragma unroll
            for (int n = 0; n < NR; n++)
#pragma unroll
                for (int j = 0; j < 4; j++)
                    red[quad][lane][(m * NR + n) * 4 + j] = acc[m][n][j];
    }
    __syncthreads();
    if (grp == 0) {
#pragma unroll
        for (int m = 0; m < MR; m++) {
            int rbase = m0 + wr * MR * 16 + m * 16 + (lane >> 4) * 4;
#pragma unroll
            for (int n = 0; n < NR; n++) {
                int col = n0 + wc * NR * 16 + n * 16 + (lane & 15);
                float bv = bias ? bias[col] : 0.f;
#pragma unroll
                for (int j = 0; j < 4; j++) {
                    long row = rbase + j;
                    float v = acc[m][n][j] + red[quad][lane][(m * NR + n) * 4 + j] + bv;
                    if (res)  v += res[row * N + col];
                    if (relu) v = fmaxf(v, 0.f);
                    long off = row * N + col + (long)blockIdx.z * cStride;
                    if (C)  C[off] = v;
                    if (Cb) Cb[off] = f2bf(v);
                }
            }
        }
    }
}

// ---------------------------------------------------------------------------
// Fused LN + Q(KV) projection + attention. Block = (head, batch), 256 thr.
// SELF:  computes Q,K,V (N=192 proj) from LN(x) in-block, K/V never hit HBM.
// !SELF: computes Q (N=64) from LN(x); K/V staged from precomputed global.
// Attention math identical to reference: s=exp(clip(qk/8,+-10)), o=sum(sv)/sum(s).
// ---------------------------------------------------------------------------
template <bool SELF>
__global__ __launch_bounds__(256) void fattn_k(
    const float* __restrict__ X, const float* __restrict__ lng,
    const float* __restrict__ lnb, const short* __restrict__ W,
    const short* __restrict__ KV, short* __restrict__ O, int causal)
{
    constexpr int NB = SELF ? 192 : 64;     // projection width
    constexpr int NR = NB / 32;             // 6 or 2 (wave cols of 16)
    constexpr int PITCH = 72;
    constexpr int ACH = 4;                  // 128*64/2048
    constexpr int BCH = NB * 64 / 2048;     // 6 or 2

    __shared__ float mu_s[128], rs_s[128], gb0[512], gb1[512], z_s[64];
    __shared__ short Q_s[128 * PITCH];
    __shared__ short K_s[128 * PITCH];
    __shared__ short VT_s[64 * 128];        // [dk][src], granule-XOR swizzled
    __shared__ __align__(16) char uni[(2 * 128 + 2 * NB) * PITCH * 2];
    short* AsB = (short*)uni;                       // As[2][128*72]
    short* BsB = AsB + 2 * 128 * PITCH;             // Bs[2][NB*72]
    short* P_s = (short*)uni;                       // [64][136] alias (post-QKV)

    int tid = threadIdx.x, lane = tid & 63, wid = tid >> 6;
    int lr = lane & 15, lg = lane >> 4;
    int h = blockIdx.x, b = blockIdx.y;
    int wr = wid >> 1, wc = wid & 1;
    int lrow = lr, koff = lg * 8;

    // ---- LN stats (rows b*128 .. +128) + gamma/beta to LDS ----
    {
        int r = tid >> 1, sub = tid & 1;
        const f32x4* row4 = (const f32x4*)(X + ((long)(b * cS + r)) * cD);
        float s = 0.f, s2 = 0.f;
        for (int i = sub; i < 128; i += 2) {
            f32x4 v = row4[i];
            s  += v[0] + v[1] + v[2] + v[3];
            s2 += v[0] * v[0] + v[1] * v[1] + v[2] * v[2] + v[3] * v[3];
        }
        s += __shfl_xor(s, 1); s2 += __shfl_xor(s2, 1);
        if (sub == 0) {
            float mu = s * (1.f / 512.f);
            float var = s2 * (1.f / 512.f) - mu * mu;
            mu_s[r] = mu; rs_s[r] = rsqrtf(var + 1e-5f);
        }
        for (int i = tid; i < 512; i += 256) { gb0[i] = lng[i]; gb1[i] = lnb[i]; }
        __syncthreads();
    }

    // ---- projection GEMM: [128 x NB] = LN(x) @ W^T slices, K=512, BK=64 ----
    f32x4 acc[4][NR];
#pragma unroll
    for (int m = 0; m < 4; m++)
#pragma unroll
        for (int n = 0; n < NR; n++) acc[m][n] = f32x4{0.f, 0.f, 0.f, 0.f};

    short8 qa[ACH], qb[BCH];
    auto stage = [&](int k0) {
#pragma unroll
        for (int i = 0; i < ACH; i++) {
            int lin = tid + i * 256, r = lin >> 3, c8 = lin & 7;
            int kg = k0 + c8 * 8;
            const f32x4* p = (const f32x4*)(X + ((long)(b * cS + r)) * cD + kg);
            f32x4 f0 = p[0], f1 = p[1];
            float mu = mu_s[r], rs = rs_s[r];
            short8 o;
#pragma unroll
            for (int j = 0; j < 4; j++) o[j]     = f2bf((f0[j] - mu) * rs * gb0[kg + j] + gb1[kg + j]);
#pragma unroll
            for (int j = 0; j < 4; j++) o[4 + j] = f2bf((f1[j] - mu) * rs * gb0[kg + 4 + j] + gb1[kg + 4 + j]);
            qa[i] = o;
        }
#pragma unroll
        for (int i = 0; i < BCH; i++) {
            int lin = tid + i * 256, r = lin >> 3, c8 = lin & 7;
            long wrow = (long)((r >> 6) * 512 + h * 64 + (r & 63));
            qb[i] = *(const short8*)&W[wrow * 512 + k0 + c8 * 8];
        }
    };
    auto writeT = [&](int buf) {
        short* Asb = AsB + buf * 128 * PITCH;
        short* Bsb = BsB + buf * NB * PITCH;
#pragma unroll
        for (int i = 0; i < ACH; i++) {
            int lin = tid + i * 256, r = lin >> 3, c8 = lin & 7;
            *(short8*)&Asb[r * PITCH + c8 * 8] = qa[i];
        }
#pragma unroll
        for (int i = 0; i < BCH; i++) {
            int lin = tid + i * 256, r = lin >> 3, c8 = lin & 7;
            *(short8*)&Bsb[r * PITCH + c8 * 8] = qb[i];
        }
    };
    auto mfmaStep = [&](int buf) {
        short* Asb = AsB + buf * 128 * PITCH;
        short* Bsb = BsB + buf * NB * PITCH;
#pragma unroll
        for (int kk = 0; kk < 64; kk += 32) {
            short8 a[4], bb[NR];
#pragma unroll
            for (int m = 0; m < 4; m++)
                a[m] = *(const short8*)&Asb[(wr * 64 + m * 16 + lrow) * PITCH + kk + koff];
#pragma unroll
            for (int n = 0; n < NR; n++)
                bb[n] = *(const short8*)&Bsb[(wc * (NB / 2) + n * 16 + lrow) * PITCH + kk + koff];
#pragma unroll
            for (int m = 0; m < 4; m++)
#pragma unroll
                for (int n = 0; n < NR; n++)
                    acc[m][n] = __builtin_amdgcn_mfma_f32_16x16x32_bf16(a[m], bb[n], acc[m][n], 0, 0, 0);
        }
    };

    stage(0);
    for (int st = 0; st < 8; st++) {
        int buf = st & 1;
        writeT(buf);
        __syncthreads();
        if (st + 1 < 8) stage((st + 1) * 64);
        mfmaStep(buf);
    }

    // ---- scatter projection to Q_s / K_s / VT_s ----
#pragma unroll
    for (int m = 0; m < 4; m++) {
        int r4 = wr * 64 + m * 16 + lg * 4;
#pragma unroll
        for (int n = 0; n < NR; n++) {
            int col = wc * (NB / 2) + n * 16 + lr;
#pragma unroll
            for (int j = 0; j < 4; j++) {
                int row = r4 + j;
                short v = f2bf(acc[m][n][j]);
                if (SELF) {
                    if (col < 64)       Q_s[row * PITCH + col] = v;
                    else if (col < 128) K_s[row * PITCH + (col - 64)] = v;
                    else {
                        int dk = col - 128;
                        int g = (row >> 3) ^ (dk >> 3);
                        VT_s[dk * 128 + g * 8 + (row & 7)] = v;
                    }
                } else {
                    Q_s[row * PITCH + col] = v;
                }
            }
        }
    }
    if (!SELF) {   // stage precomputed K/V (bf16 global) for this (b,h)
        const short* Vp = KV + (long)cN * cD;
        long kb = ((long)b * cS) * cD + h * 64;
#pragma unroll
        for (int i = 0; i < 4; i++) {
            int lin = tid + i * 256, t = lin >> 3, c8 = lin & 7;
            *(short8*)&K_s[t * PITCH + c8 * 8] = *(const short8*)&KV[kb + (long)t * cD + c8 * 8];
            short8 v = *(const short8*)&Vp[kb + (long)t * cD + c8 * 8];
#pragma unroll
            for (int j = 0; j < 8; j++) {
                int dk = c8 * 8 + j;
                int g = (t >> 3) ^ (dk >> 3);
                VT_s[dk * 128 + g * 8 + (t & 7)] = v[j];
            }
        }
    }
    __syncthreads();

    // ---- attention, two 64-dst halves ----
    for (int h2 = 0; h2 < 2; h2++) {
        f32x4 sacc[8];
#pragma unroll
        for (int n = 0; n < 8; n++) sacc[n] = f32x4{0.f, 0.f, 0.f, 0.f};
#pragma unroll
        for (int kk = 0; kk < 64; kk += 32) {
            short8 a = *(const short8*)&Q_s[(h2 * 64 + wid * 16 + lr) * PITCH + kk + lg * 8];
#pragma unroll
            for (int n = 0; n < 8; n++) {
                short8 bf = *(const short8*)&K_s[(n * 16 + lr) * PITCH + kk + lg * 8];
                sacc[n] = __builtin_amdgcn_mfma_f32_16x16x32_bf16(a, bf, sacc[n], 0, 0, 0);
            }
        }
        float z[4] = {0.f, 0.f, 0.f, 0.f};
#pragma unroll
        for (int n = 0; n < 8; n++) {
            int src = n * 16 + lr;
#pragma unroll
            for (int j = 0; j < 4; j++) {
                int dst = h2 * 64 + wid * 16 + lg * 4 + j;
                float s = sacc[n][j] * 0.125f;
                s = __expf(fminf(fmaxf(s, -10.f), 10.f));
                if (causal && src > dst) s = 0.f;
                sacc[n][j] = s;
                z[j] += s;
            }
        }
#pragma unroll
        for (int j = 0; j < 4; j++) {
            z[j] += __shfl_xor(z[j], 1); z[j] += __shfl_xor(z[j], 2);
            z[j] += __shfl_xor(z[j], 4); z[j] += __shfl_xor(z[j], 8);
        }
#pragma unroll
        for (int n = 0; n < 8; n++) {
            int src = n * 16 + lr;
#pragma unroll
            for (int j = 0; j < 4; j++)
                P_s[(wid * 16 + lg * 4 + j) * 136 + src] = f2bf(sacc[n][j]);
        }
        if (lr == 0) {
#pragma unroll
            for (int j = 0; j < 4; j++) z_s[wid * 16 + lg * 4 + j] = z[j];
        }
        __syncthreads();

        f32x4 oacc[4];
#pragma unroll
        for (int n = 0; n < 4; n++) oacc[n] = f32x4{0.f, 0.f, 0.f, 0.f};
#pragma unroll
        for (int kk = 0; kk < 128; kk += 32) {
            int dkr = wid * 16 + lr;
            int g = ((kk >> 3) + lg) ^ (dkr >> 3);
            short8 a = *(const short8*)&VT_s[dkr * 128 + g * 8];
#pragma unroll
            for (int n = 0; n < 4; n++) {
                short8 bf = *(const short8*)&P_s[(n * 16 + lr) * 136 + kk + lg * 8];
                oacc[n] = __builtin_amdgcn_mfma_f32_16x16x32_bf16(a, bf, oacc[n], 0, 0, 0);
            }
        }
#pragma unroll
        for (int n = 0; n < 4; n++) {
            int dl = n * 16 + lr;
            float zz = z_s[dl];
#pragma unroll
            for (int j = 0; j < 4; j++) {
                int dk = wid * 16 + lg * 4 + j;
                O[((long)(b * cS + h2 * 64 + dl)) * cD + h * 64 + dk] = f2bf(oacc[n][j] / zz);
            }
        }
        __syncthreads();
    }
}

// ---------------------------------------------------------------------------
// Generator GEMM with 32x32x16 MFMA (2x MACs per LDS byte vs 16x16).
// 256 thr = 4 waves (2x2), wave tile 64x64 (2x2 of 32x32), block 128x128.
// A bf16 [M][K]; Bt bf16 [N][K]; C = A@B + bias (fp32 out). XCD swizzle.
// ---------------------------------------------------------------------------
__global__ __launch_bounds__(256) void gen32_k(
    const short* __restrict__ A, const short* __restrict__ Bt,
    const float* __restrict__ bias, float* __restrict__ C, int N, int K)
{
    constexpr int PITCH = 72;
    constexpr int ACH = 4, BCH = 4;    // 128*64/2048
    __shared__ short As[2][128 * PITCH];
    __shared__ short Bs[2][128 * PITCH];

    int bx = blockIdx.x, by = blockIdx.y;
    {   // XCD swizzle (grid 250x4 = 1000, 1000 % 8 == 0)
        int nb = gridDim.x * gridDim.y;
        int bid = by * gridDim.x + bx;
        int w = (bid & 7) * (nb >> 3) + (bid >> 3);
        by = w % gridDim.y; bx = w / gridDim.y;
    }
    int tid = threadIdx.x;
    int lane = tid & 63, wid = tid >> 6;
    int wr = wid >> 1, wc = wid & 1;
    int m0 = by * 128, n0 = bx * 128;
    int l31 = lane & 31, l5 = lane >> 5;

    f32x16 acc[2][2];
#pragma unroll
    for (int m = 0; m < 2; m++)
#pragma unroll
        for (int n = 0; n < 2; n++)
#pragma unroll
            for (int r = 0; r < 16; r++) acc[m][n][r] = 0.f;

    short8 qa0[ACH], qa1[ACH], qb0[BCH], qb1[BCH];
    auto stage = [&](int k0, short8 (&qa)[ACH], short8 (&qb)[BCH]) {
#pragma unroll
        for (int i = 0; i < ACH; i++) {
            int lin = tid + i * 256, r = lin >> 3, c8 = lin & 7;
            qa[i] = *(const short8*)&A[(long)(m0 + r) * K + k0 + c8 * 8];
        }
#pragma unroll
        for (int i = 0; i < BCH; i++) {
            int lin = tid + i * 256, r = lin >> 3, c8 = lin & 7;
            qb[i] = *(const short8*)&Bt[(long)(n0 + r) * K + k0 + c8 * 8];
        }
    };
    auto writeT = [&](int buf, short8 (&qa)[ACH], short8 (&qb)[BCH]) {
#pragma unroll
        for (int i = 0; i < ACH; i++) {
            int lin = tid + i * 256, r = lin >> 3, c8 = lin & 7;
            *(short8*)&As[buf][r * PITCH + c8 * 8] = qa[i];
        }
#pragma unroll
        for (int i = 0; i < BCH; i++) {
            int lin = tid + i * 256, r = lin >> 3, c8 = lin & 7;
            *(short8*)&Bs[buf][r * PITCH + c8 * 8] = qb[i];
        }
    };
    auto mfmaStep = [&](int buf) {
#pragma unroll
        for (int kk = 0; kk < 64; kk += 16) {
            short8 a[2], b[2];
#pragma unroll
            for (int m = 0; m < 2; m++)
                a[m] = *(const short8*)&As[buf][(wr * 64 + m * 32 + l31) * PITCH + kk + l5 * 8];
#pragma unroll
            for (int n = 0; n < 2; n++)
                b[n] = *(const short8*)&Bs[buf][(wc * 64 + n * 32 + l31) * PITCH + kk + l5 * 8];
#pragma unroll
            for (int m = 0; m < 2; m++)
#pragma unroll
                for (int n = 0; n < 2; n++)
                    acc[m][n] = __builtin_amdgcn_mfma_f32_32x32x16_bf16(a[m], b[n], acc[m][n], 0, 0, 0);
        }
    };

    const int steps = K >> 6;   // 8
    stage(0, qa0, qb0);
    stage(64, qa1, qb1);
    int st = 0;
    for (;;) {
        writeT(0, qa0, qb0);
        __syncthreads();
        if (st + 2 < steps) stage((st + 2) * 64, qa0, qb0);
        mfmaStep(0);
        st++; if (st >= steps) break;

        writeT(1, qa1, qb1);
        __syncthreads();
        if (st + 2 < steps) stage((st + 2) * 64, qa1, qb1);
        mfmaStep(1);
        st++; if (st >= steps) break;
    }

    // epilogue: 32x32 C/D layout col=lane&31, row=(r&3)+8*(r>>2)+4*(lane>>5)
#pragma unroll
    for (int m = 0; m < 2; m++) {
#pragma unroll
        for (int n = 0; n < 2; n++) {
            int col = n0 + wc * 64 + n * 32 + l31;
            float bv = bias[col];
#pragma unroll
            for (int r = 0; r < 16; r++) {
                int row = m0 + wr * 64 + m * 32 + (r & 3) + 8 * (r >> 2) + 4 * l5;
                C[(long)row * N + col] = acc[m][n][r] + bv;
            }
        }
    }
}

// ---------------------------------------------------------------------------
// In-place row log_softmax over V=32000: online max+sum (1 read) + write pass
// ---------------------------------------------------------------------------
__global__ __launch_bounds__(256) void lsm_k(float* __restrict__ X)
{
    __shared__ float rm[256], rs[256];
    int row = blockIdx.x, tid = threadIdx.x;
    f32x4* x4 = (f32x4*)(X + (long)row * cV);
    constexpr int NV = cV / 4;

    float m = -1e30f, s = 0.f;
    for (int i = tid; i < NV; i += 256) {
        f32x4 v = x4[i];
        float cm = fmaxf(fmaxf(v[0], v[1]), fmaxf(v[2], v[3]));
        float nm = fmaxf(m, cm);
        s = s * __expf(m - nm)
          + __expf(v[0] - nm) + __expf(v[1] - nm)
          + __expf(v[2] - nm) + __expf(v[3] - nm);
        m = nm;
    }
    rm[tid] = m; rs[tid] = s;
    __syncthreads();
    for (int st = 128; st > 0; st >>= 1) {
        if (tid < st) {
            float m2 = rm[tid + st], s2 = rs[tid + st];
            float nm = fmaxf(rm[tid], m2);
            rs[tid] = rs[tid] * __expf(rm[tid] - nm) + s2 * __expf(m2 - nm);
            rm[tid] = nm;
        }
        __syncthreads();
    }
    float lse = rm[0] + __logf(rs[0]);

    for (int i = tid; i < NV; i += 256) {
        f32x4 v = x4[i];
        v[0] -= lse; v[1] -= lse; v[2] -= lse; v[3] -= lse;
        x4[i] = v;
    }
}

// ---------------------------------------------------------------------------
extern "C" void kernel_launch(void* const* d_in, const int* in_sizes, int n_in,
                              void* d_out, int out_size, void* d_ws, size_t ws_size,
                              hipStream_t stream)
{
    const float* src_emb  = (const float*)d_in[0];
    const float* tgt_emb  = (const float*)d_in[1];
    const float* enc_Wqkv = (const float*)d_in[2];
    const float* enc_Wo   = (const float*)d_in[3];
    const float* enc_ln1  = (const float*)d_in[4];
    const float* enc_W1   = (const float*)d_in[5];
    const float* enc_b1   = (const float*)d_in[6];
    const float* enc_W2   = (const float*)d_in[7];
    const float* enc_b2   = (const float*)d_in[8];
    const float* enc_ln2  = (const float*)d_in[9];
    const float* enc_lnf  = (const float*)d_in[10];
    const float* dec_Wqkv = (const float*)d_in[11];
    const float* dec_Wo   = (const float*)d_in[12];
    const float* dec_ln1  = (const float*)d_in[13];
    const float* dec_cWq  = (const float*)d_in[14];
    const float* dec_cWkv = (const float*)d_in[15];
    const float* dec_cWo  = (const float*)d_in[16];
    const float* dec_ln2  = (const float*)d_in[17];
    const float* dec_W1   = (const float*)d_in[18];
    const float* dec_b1   = (const float*)d_in[19];
    const float* dec_W2   = (const float*)d_in[20];
    const float* dec_b2   = (const float*)d_in[21];
    const float* dec_ln3  = (const float*)d_in[22];
    const float* dec_lnf  = (const float*)d_in[23];
    const float* gen_W    = (const float*)d_in[24];
    const float* gen_b    = (const float*)d_in[25];
    const int* src_tok    = (const int*)d_in[26];
    const int* tgt_tok    = (const int*)d_in[27];
    // edge lists (28..33): fixed structure (full / causal) -> unused

    const long ND = (long)cN * cD;          // 262144
    const long DD = (long)cD * cD;          // 262144
    const long DF = (long)cD * cF;          // 1048576

    // fp32 region
    float* x_e = (float*)d_ws;
    float* x_d = x_e + ND;

    // bf16 region
    short* ob_bf = (short*)(x_d + ND);      // [N,D] attn out
    short* hb_bf = ob_bf + ND;              // [N,F]
    short* kvc   = hb_bf + (long)cN * cF;   // [4][N,D] cross K/V (l0k,l0v,l1k,l1v)
    short* xn_bf = kvc + 4 * ND;            // [N,D]
    // transposed bf16 weights
    short* wDD  = xn_bf + ND;               // 24 x [D][D]
    short* wDF  = wDD + 24 * DD;            // 4  x [F][D]  (W1 slices)
    short* wFD  = wDF + 4 * DF;             // 4  x [D][F]  (W2 slices)
    short* genT = wFD + 4 * DF;             // [V][D]

    // DD slice order: 0-5 enc_Wqkv | 6-7 enc_Wo | 8-13 dec_Wqkv | 14-15 dec_Wo
    //                 16-17 dec_cWq | 18-21 dec_cWkv | 22-23 dec_cWo
    {
        TCP p{};
        int i = 0;
        for (int j = 0; j < 6; j++) p.s[i++] = enc_Wqkv + (long)j * DD;
        for (int j = 0; j < 2; j++) p.s[i++] = enc_Wo   + (long)j * DD;
        for (int j = 0; j < 6; j++) p.s[i++] = dec_Wqkv + (long)j * DD;
        for (int j = 0; j < 2; j++) p.s[i++] = dec_Wo   + (long)j * DD;
        for (int j = 0; j < 2; j++) p.s[i++] = dec_cWq  + (long)j * DD;
        for (int j = 0; j < 4; j++) p.s[i++] = dec_cWkv + (long)j * DD;
        for (int j = 0; j < 2; j++) p.s[i++] = dec_cWo  + (long)j * DD;
        tconv_k<<<dim3(cD / 64, cD / 64, 24), 256, 0, stream>>>(p, wDD, cD, cD);
    }
    {
        TCP p{};
        p.s[0] = enc_W1; p.s[1] = enc_W1 + DF; p.s[2] = dec_W1; p.s[3] = dec_W1 + DF;
        tconv_k<<<dim3(cF / 64, cD / 64, 4), 256, 0, stream>>>(p, wDF, cD, cF);
    }
    {
        TCP p{};
        p.s[0] = enc_W2; p.s[1] = enc_W2 + DF; p.s[2] = dec_W2; p.s[3] = dec_W2 + DF;
        tconv_k<<<dim3(cD / 64, cF / 64, 4), 256, 0, stream>>>(p, wFD, cF, cD);
    }
    {
        TCP p{};
        p.s[0] = gen_W;
        tconv_k<<<dim3(cV / 64, cD / 64, 1), 256, 0, stream>>>(p, genT, cD, cV);
    }

    embed_k<<<cN, 256, 0, stream>>>(src_emb, src_tok, x_e);
    embed_k<<<cN, 256, 0, stream>>>(tgt_emb, tgt_tok, x_d);

    dim3 gDD(cD / 32, cN / 32);            // 256 blocks, <1,1>
    dim3 gFFN1(cF / 64, cN / 64);          // 256 blocks, <2,2>
    dim3 gAttn(cH, cB);                    // 32 blocks

    // ---- encoder ----
    for (int l = 0; l < cL; l++) {
        fattn_k<true><<<gAttn, 256, 0, stream>>>(
            x_e, enc_ln1 + (long)(2 * l) * cD, enc_ln1 + (long)(2 * l + 1) * cD,
            wDD + (long)(3 * l) * DD, nullptr, ob_bf, 0);
        gemm8_k<1, 1, false><<<gDD, 512, 0, stream>>>(
            ob_bf, nullptr, nullptr, nullptr, wDD + (long)(6 + l) * DD,
            nullptr, x_e, x_e, nullptr, cD, cD, 0, 0, 0);
        gemm8_k<2, 2, true><<<gFFN1, 512, 0, stream>>>(
            nullptr, x_e, enc_ln2 + (long)(2 * l) * cD, enc_ln2 + (long)(2 * l + 1) * cD,
            wDF + (long)l * DF, enc_b1 + (long)l * cF, nullptr, nullptr, hb_bf,
            cF, cD, 1, 0, 0);
        gemm8_k<1, 1, false><<<gDD, 512, 0, stream>>>(
            hb_bf, nullptr, nullptr, nullptr, wFD + (long)l * DF,
            enc_b2 + (long)l * cD, x_e, x_e, nullptr, cD, cF, 0, 0, 0);
    }

    // ---- cross K/V for both decoder layers (enc_lnf fused), z=4 ----
    gemm8_k<1, 1, true><<<dim3(cD / 32, cN / 32, 4), 512, 0, stream>>>(
        nullptr, x_e, enc_lnf, enc_lnf + cD,
        wDD + 18 * DD, nullptr, nullptr, nullptr, kvc, cD, cD, 0, DD, ND);

    // ---- decoder ----
    for (int l = 0; l < cL; l++) {
        fattn_k<true><<<gAttn, 256, 0, stream>>>(
            x_d, dec_ln1 + (long)(2 * l) * cD, dec_ln1 + (long)(2 * l + 1) * cD,
            wDD + (long)(8 + 3 * l) * DD, nullptr, ob_bf, 1);
        gemm8_k<1, 1, false><<<gDD, 512, 0, stream>>>(
            ob_bf, nullptr, nullptr, nullptr, wDD + (long)(14 + l) * DD,
            nullptr, x_d, x_d, nullptr, cD, cD, 0, 0, 0);

        fattn_k<false><<<gAttn, 256, 0, stream>>>(
            x_d, dec_ln2 + (long)(2 * l) * cD, dec_ln2 + (long)(2 * l + 1) * cD,
            wDD + (long)(16 + l) * DD, kvc + (long)(2 * l) * ND, ob_bf, 0);
        gemm8_k<1, 1, false><<<gDD, 512, 0, stream>>>(
            ob_bf, nullptr, nullptr, nullptr, wDD + (long)(22 + l) * DD,
            nullptr, x_d, x_d, nullptr, cD, cD, 0, 0, 0);

        gemm8_k<2, 2, true><<<gFFN1, 512, 0, stream>>>(
            nullptr, x_d, dec_ln3 + (long)(2 * l) * cD, dec_ln3 + (long)(2 * l + 1) * cD,
            wDF + (long)(2 + l) * DF, dec_b1 + (long)l * cF, nullptr, nullptr, hb_bf,
            cF, cD, 1, 0, 0);
        gemm8_k<1, 1, false><<<gDD, 512, 0, stream>>>(
            hb_bf, nullptr, nullptr, nullptr, wFD + (long)(2 + l) * DF,
            dec_b2 + (long)l * cD, x_d, x_d, nullptr, cD, cF, 0, 0, 0);
    }

    // ---- final LN + generator (32x32 MFMA) + log_softmax ----
    ln_k<<<cN, 256, 0, stream>>>(x_d, dec_lnf, dec_lnf + cD, xn_bf);
    gen32_k<<<dim3(cV / 128, cN / 128), 256, 0, stream>>>(
        xn_bf, genT, gen_b, (float*)d_out, cV, cD);
    lsm_k<<<cN, 256, 0, stream>>>((float*)d_out);
}

// Round 7
// 356.983 us; speedup vs baseline: 1.2628x; 1.2628x over previous
//
#include <hip/hip_runtime.h>
#include <cstddef>

// Problem constants (from reference)
constexpr int cB = 4, cS = 128, cD = 512, cH = 8, cDK = 64, cF = 2048, cL = 2, cV = 32000;
constexpr int cN = cB * cS; // 512

typedef __attribute__((ext_vector_type(8)))  short short8;  // 8 x bf16 (MFMA frag)
typedef __attribute__((ext_vector_type(4)))  float f32x4;
typedef __attribute__((ext_vector_type(16))) float f32x16;  // 32x32 MFMA acc

__device__ __forceinline__ short f2bf(float x) {            // RNE fp32->bf16
    unsigned u = __builtin_bit_cast(unsigned, x);
    unsigned r = (u + 0x7fffu + ((u >> 16) & 1u)) >> 16;
    return (short)r;
}
__device__ __forceinline__ short f2h(float x) {             // fp32 -> fp16 bits
    return __builtin_bit_cast(short, (_Float16)x);
}
__device__ __forceinline__ float h2f(short s) {
    return (float)__builtin_bit_cast(_Float16, s);
}

// Raw barrier: waits LDS ops only (lgkmcnt). Global loads stay IN FLIGHT
// across the barrier (unlike __syncthreads, where the compiler emits
// s_waitcnt vmcnt(0) -> drains the prefetch queue every K-step).
__device__ __forceinline__ void bar_lgkm() {
    asm volatile("s_waitcnt lgkmcnt(0)" ::: "memory");
    __builtin_amdgcn_s_barrier();
    asm volatile("" ::: "memory");
}

// ---------------------------------------------------------------------------
// Embedding + positional encoding, both streams in one launch (z = 0/1)
// ---------------------------------------------------------------------------
__global__ __launch_bounds__(256) void embed_k(const float* __restrict__ e0,
                                               const int* __restrict__ t0,
                                               float* __restrict__ X0,
                                               const float* __restrict__ e1,
                                               const int* __restrict__ t1,
                                               float* __restrict__ X1)
{
    const float* emb = blockIdx.z ? e1 : e0;
    const int* tok   = blockIdx.z ? t1 : t0;
    float* X         = blockIdx.z ? X1 : X0;
    int n = blockIdx.x;
    int tid = threadIdx.x;
    int t = tok[n];
    int pos = n & (cS - 1);
    const float scale = 22.62741699796952f; // sqrt(512)
    for (int d = tid; d < cD; d += 256) {
        int i2 = d & ~1;
        float div = expf(-9.210340371976184f * (float)i2 / (float)cD);
        float arg = (float)pos * div;
        float p = (d & 1) ? cosf(arg) : sinf(arg);
        X[(long)n * cD + d] = emb[(long)t * cD + d] * scale + p;
    }
}

// ---------------------------------------------------------------------------
// LayerNorm -> bf16 (used once, before the generator GEMM)
// ---------------------------------------------------------------------------
__global__ __launch_bounds__(256) void ln_k(const float* __restrict__ X,
                                            const float* __restrict__ g,
                                            const float* __restrict__ bta,
                                            short* __restrict__ Yb)
{
    __shared__ float red[256];
    int row = blockIdx.x, tid = threadIdx.x;
    const float* x = X + (long)row * cD;
    float v0 = x[tid], v1 = x[tid + 256];

    red[tid] = v0 + v1;
    __syncthreads();
    for (int st = 128; st > 0; st >>= 1) { if (tid < st) red[tid] += red[tid + st]; __syncthreads(); }
    float mu = red[0] * (1.0f / (float)cD);
    __syncthreads();

    float d0 = v0 - mu, d1 = v1 - mu;
    red[tid] = d0 * d0 + d1 * d1;
    __syncthreads();
    for (int st = 128; st > 0; st >>= 1) { if (tid < st) red[tid] += red[tid + st]; __syncthreads(); }
    float var = red[0] * (1.0f / (float)cD);
    float rs = rsqrtf(var + 1e-5f);

    Yb[(long)row * cD + tid]       = f2bf(g[tid]       * d0 * rs + bta[tid]);
    Yb[(long)row * cD + tid + 256] = f2bf(g[tid + 256] * d1 * rs + bta[tid + 256]);
}

// ---------------------------------------------------------------------------
// Batched transpose-convert: z slices fp32 [K][N] -> bf16 [N][K] contiguous.
// ---------------------------------------------------------------------------
struct TCP { const float* s[24]; };

__global__ __launch_bounds__(256) void tconv_k(TCP ptrs, short* __restrict__ dst,
                                               int K, int N)
{
    __shared__ float t[64][65];
    const float* s = ptrs.s[blockIdx.z];
    short* d = dst + (long)blockIdx.z * K * N;
    int k0 = blockIdx.y * 64, n0 = blockIdx.x * 64;
    int tid = threadIdx.x;
    const f32x4* s4 = (const f32x4*)s;
#pragma unroll
    for (int i = 0; i < 4; i++) {
        int lin = tid + i * 256;
        int r = lin >> 4, c4 = lin & 15;
        f32x4 v = s4[(long)(k0 + r) * (N >> 2) + (n0 >> 2) + c4];
        t[r][c4 * 4 + 0] = v[0]; t[r][c4 * 4 + 1] = v[1];
        t[r][c4 * 4 + 2] = v[2]; t[r][c4 * 4 + 3] = v[3];
    }
    __syncthreads();
#pragma unroll
    for (int i = 0; i < 2; i++) {
        int lin = tid + i * 256;
        int r = lin >> 3, c8 = lin & 7;
        short8 o;
#pragma unroll
        for (int j = 0; j < 8; j++) o[j] = f2bf(t[c8 * 8 + j][r]);
        *(short8*)&d[(long)(n0 + r) * K + k0 + c8 * 8] = o;
    }
}

// ---------------------------------------------------------------------------
// bf16 MFMA GEMM, double-buffered LDS + depth-2 register prefetch, RAW
// barriers (lgkmcnt only) so prefetch loads survive the per-step barrier.
//   C = act(LN?(A) @ B + bias) + res
// A (bf16) row-major [M][K] or fp32 with fused LN; Bt bf16 transposed [N][K].
// 256 threads = 4 waves (2x2); block tile (MR*32) x (NR*32); BK=64.
// ---------------------------------------------------------------------------
template <int MR, int NR, bool LNF>
__global__ __launch_bounds__(256) void gemm_k(
    const short* __restrict__ Abf, const float* __restrict__ Af,
    const float* __restrict__ lng, const float* __restrict__ lnb,
    const short* __restrict__ Bt,
    const float* __restrict__ bias, const float* __restrict__ res,
    float* __restrict__ C, short* __restrict__ Cb,
    int N, int K, int relu, long btStride, long cStride, int swz)
{
    constexpr int BM = MR * 32, BN = NR * 32, BK = 64, PITCH = BK + 8;
    constexpr int ACH = (BM * BK) / (8 * 256);   // short8 chunks / thread
    constexpr int BCH = (BN * BK) / (8 * 256);
    static_assert(ACH >= 1 && BCH >= 1, "tile too small");
    __shared__ short As[2][BM * PITCH];
    __shared__ short Bs[2][BN * PITCH];
    __shared__ float mu_s[BM], rs_s[BM];
    __shared__ float gb_s[2][512];               // LN gamma/beta (LNF: K==512)

    int bx = blockIdx.x, by = blockIdx.y;
    if (swz) {  // XCD grouping (grid count % 8 == 0 at swz call sites)
        int nb = gridDim.x * gridDim.y;
        int bid = by * gridDim.x + bx;
        int w = (bid & 7) * (nb >> 3) + (bid >> 3);
        by = w % gridDim.y; bx = w / gridDim.y;
    }

    const short* Bm = Bt + (long)blockIdx.z * btStride;
    int tid = threadIdx.x;
    int lane = tid & 63, wid = tid >> 6;
    int wr = wid >> 1, wc = wid & 1;
    int m0 = by * BM, n0 = bx * BN;
    int lrow = lane & 15, koff = (lane >> 4) * 8;

    f32x4 acc[MR][NR];
#pragma unroll
    for (int m = 0; m < MR; m++)
#pragma unroll
        for (int n = 0; n < NR; n++) acc[m][n] = f32x4{0.f, 0.f, 0.f, 0.f};

    // register queues (two named slots each)
    short8 qa0[ACH], qa1[ACH], qb0[BCH], qb1[BCH];
    f32x4 fa0[LNF ? ACH * 2 : 1], fa1[LNF ? ACH * 2 : 1];

    auto stageA = [&](int k0, short8 (&qa)[ACH], f32x4 (&fa)[LNF ? ACH * 2 : 1]) {
#pragma unroll
        for (int i = 0; i < ACH; i++) {
            int lin = tid + i * 256, r = lin >> 3, c8 = lin & 7;
            if constexpr (LNF) {
                const f32x4* p = (const f32x4*)(Af + (long)(m0 + r) * K + k0 + c8 * 8);
                fa[2 * i] = p[0]; fa[2 * i + 1] = p[1];
            } else {
                qa[i] = *(const short8*)&Abf[(long)(m0 + r) * K + k0 + c8 * 8];
            }
        }
    };
    auto stageB = [&](int k0, short8 (&qb)[BCH]) {
#pragma unroll
        for (int i = 0; i < BCH; i++) {
            int lin = tid + i * 256, r = lin >> 3, c8 = lin & 7;
            qb[i] = *(const short8*)&Bm[(long)(n0 + r) * K + k0 + c8 * 8];
        }
    };
    auto writeT = [&](int buf, int k0, short8 (&qa)[ACH],
                      f32x4 (&fa)[LNF ? ACH * 2 : 1], short8 (&qb)[BCH]) {
#pragma unroll
        for (int i = 0; i < ACH; i++) {
            int lin = tid + i * 256, r = lin >> 3, c8 = lin & 7;
            if constexpr (LNF) {
                float mu = mu_s[r], rs = rs_s[r];
                short8 o;
#pragma unroll
                for (int j = 0; j < 4; j++)
                    o[j] = f2bf((fa[2 * i][j] - mu) * rs * gb_s[0][k0 + c8 * 8 + j] + gb_s[1][k0 + c8 * 8 + j]);
#pragma unroll
                for (int j = 0; j < 4; j++)
                    o[4 + j] = f2bf((fa[2 * i + 1][j] - mu) * rs * gb_s[0][k0 + c8 * 8 + 4 + j] + gb_s[1][k0 + c8 * 8 + 4 + j]);
                *(short8*)&As[buf][r * PITCH + c8 * 8] = o;
            } else {
                *(short8*)&As[buf][r * PITCH + c8 * 8] = qa[i];
            }
        }
#pragma unroll
        for (int i = 0; i < BCH; i++) {
            int lin = tid + i * 256, r = lin >> 3, c8 = lin & 7;
            *(short8*)&Bs[buf][r * PITCH + c8 * 8] = qb[i];
        }
    };
    auto mfmaStep = [&](int buf) {
#pragma unroll
        for (int kk = 0; kk < BK; kk += 32) {
            short8 a[MR], b[NR];
#pragma unroll
            for (int m = 0; m < MR; m++)
                a[m] = *(const short8*)&As[buf][(wr * MR * 16 + m * 16 + lrow) * PITCH + kk + koff];
#pragma unroll
            for (int n = 0; n < NR; n++)
                b[n] = *(const short8*)&Bs[buf][(wc * NR * 16 + n * 16 + lrow) * PITCH + kk + koff];
#pragma unroll
            for (int m = 0; m < MR; m++)
#pragma unroll
                for (int n = 0; n < NR; n++)
                    acc[m][n] = __builtin_amdgcn_mfma_f32_16x16x32_bf16(a[m], b[n], acc[m][n], 0, 0, 0);
        }
    };

    // issue first two stages ASAP
    stageA(0, qa0, fa0); stageB(0, qb0);
    if (BK < K) { stageA(BK, qa1, fa1); stageB(BK, qb1); }

    if constexpr (LNF) {   // LN stats + gamma/beta staging (K==512 at LNF sites)
        constexpr int TPR = 256 / BM;
        int r = tid / TPR, sub = tid % TPR;
        const f32x4* row4 = (const f32x4*)(Af + (long)(m0 + r) * K);
        float s = 0.f, s2 = 0.f;
        for (int i = sub; i < (K >> 2); i += TPR) {
            f32x4 v = row4[i];
            s  += v[0] + v[1] + v[2] + v[3];
            s2 += v[0] * v[0] + v[1] * v[1] + v[2] * v[2] + v[3] * v[3];
        }
#pragma unroll
        for (int o = TPR >> 1; o > 0; o >>= 1) {
            s += __shfl_xor(s, o); s2 += __shfl_xor(s2, o);
        }
        if (sub == 0) {
            float mu = s / (float)K;
            float var = s2 / (float)K - mu * mu;
            mu_s[r] = mu; rs_s[r] = rsqrtf(var + 1e-5f);
        }
        for (int i = tid; i < 512; i += 256) {
            gb_s[0][i] = lng[i]; gb_s[1][i] = lnb[i];
        }
        bar_lgkm();
    }

    int k0 = 0;
    for (;;) {
        writeT(0, k0, qa0, fa0, qb0);
        if (k0 + 2 * BK < K) { stageA(k0 + 2 * BK, qa0, fa0); stageB(k0 + 2 * BK, qb0); }
        bar_lgkm();                            // lgkm only: prefetch survives
        mfmaStep(0);
        k0 += BK; if (k0 >= K) break;

        writeT(1, k0, qa1, fa1, qb1);
        if (k0 + 2 * BK < K) { stageA(k0 + 2 * BK, qa1, fa1); stageB(k0 + 2 * BK, qb1); }
        bar_lgkm();
        mfmaStep(1);
        k0 += BK; if (k0 >= K) break;
    }

    // epilogue: C/D layout col=lane&15, row=(lane>>4)*4+j  [m89]
#pragma unroll
    for (int m = 0; m < MR; m++) {
        int rbase = m0 + wr * MR * 16 + m * 16 + (lane >> 4) * 4;
#pragma unroll
        for (int n = 0; n < NR; n++) {
            int col = n0 + wc * NR * 16 + n * 16 + (lane & 15);
            float bv = bias ? bias[col] : 0.f;
#pragma unroll
            for (int j = 0; j < 4; j++) {
                long row = rbase + j;
                float v = acc[m][n][j] + bv;
                if (res)  v += res[row * N + col];
                if (relu) v = fmaxf(v, 0.f);
                long off = row * N + col + (long)blockIdx.z * cStride;
                if (C)  C[off] = v;
                if (Cb) Cb[off] = f2bf(v);
            }
        }
    }
}

// ---------------------------------------------------------------------------
// MFMA attention: block = (head, batch, dst-half of 64). 256 threads, 4 waves.
// q,k,v,o bf16 [token][H*DK]. Exact reference math:
//   s = exp(clip(q.k/8, +-10)); o = sum(s*v)/sum(s); causal masks src>dst.
// ---------------------------------------------------------------------------
__global__ __launch_bounds__(256) void attn_k(const short* __restrict__ Q,
                                              const short* __restrict__ Km,
                                              const short* __restrict__ Vm,
                                              short* __restrict__ O, int causal)
{
    __shared__ short q_s[64 * 72];     // [dst][dk]  pitch 72
    __shared__ short k_s[128 * 72];    // [src][dk]  pitch 72
    __shared__ short vt_s[64 * 128];   // [dk][src]  granule-swizzled, pitch 128
    __shared__ short p_s[64 * 136];    // [dst][src] pitch 136
    __shared__ float z_s[64];

    int tid = threadIdx.x, lane = tid & 63, wid = tid >> 6;
    int lr = lane & 15, lg = lane >> 4;
    int h = blockIdx.x, b = blockIdx.y, dstBase = blockIdx.z * 64;
    const int RS = cH * cDK; // 512
    long qbase = ((long)b * cS + dstBase) * RS + h * cDK;
    long kbase = ((long)b * cS) * RS + h * cDK;

#pragma unroll
    for (int i = 0; i < 2; i++) {
        int lin = tid + i * 256, t = lin >> 3, c8 = lin & 7;
        *(short8*)&q_s[t * 72 + c8 * 8] = *(const short8*)&Q[qbase + (long)t * RS + c8 * 8];
    }
#pragma unroll
    for (int i = 0; i < 4; i++) {
        int lin = tid + i * 256, t = lin >> 3, c8 = lin & 7;
        *(short8*)&k_s[t * 72 + c8 * 8] = *(const short8*)&Km[kbase + (long)t * RS + c8 * 8];
    }
#pragma unroll
    for (int i = 0; i < 4; i++) {
        int lin = tid + i * 256, src = lin >> 3, c8 = lin & 7;
        short8 v = *(const short8*)&Vm[kbase + (long)src * RS + c8 * 8];
#pragma unroll
        for (int j = 0; j < 8; j++) {
            int dk = c8 * 8 + j;
            int g = (src >> 3) ^ (dk >> 3);
            vt_s[dk * 128 + g * 8 + (src & 7)] = v[j];
        }
    }
    bar_lgkm();

    // ---- S = q @ k^T : wave computes 16 dst rows x 128 src ----
    f32x4 sacc[8];
#pragma unroll
    for (int n = 0; n < 8; n++) sacc[n] = f32x4{0.f, 0.f, 0.f, 0.f};
#pragma unroll
    for (int kk = 0; kk < 64; kk += 32) {
        short8 a = *(const short8*)&q_s[(wid * 16 + lr) * 72 + kk + lg * 8];
#pragma unroll
        for (int n = 0; n < 8; n++) {
            short8 bf = *(const short8*)&k_s[(n * 16 + lr) * 72 + kk + lg * 8];
            sacc[n] = __builtin_amdgcn_mfma_f32_16x16x32_bf16(a, bf, sacc[n], 0, 0, 0);
        }
    }
    float z[4] = {0.f, 0.f, 0.f, 0.f};
#pragma unroll
    for (int n = 0; n < 8; n++) {
        int src = n * 16 + lr;
#pragma unroll
        for (int j = 0; j < 4; j++) {
            int dst = dstBase + wid * 16 + lg * 4 + j;
            float s = sacc[n][j] * 0.125f;
            s = __expf(fminf(fmaxf(s, -10.f), 10.f));
            if (causal && src > dst) s = 0.f;
            sacc[n][j] = s;
            z[j] += s;
        }
    }
#pragma unroll
    for (int j = 0; j < 4; j++) {
        z[j] += __shfl_xor(z[j], 1); z[j] += __shfl_xor(z[j], 2);
        z[j] += __shfl_xor(z[j], 4); z[j] += __shfl_xor(z[j], 8);
    }
#pragma unroll
    for (int n = 0; n < 8; n++) {
        int src = n * 16 + lr;
#pragma unroll
        for (int j = 0; j < 4; j++)
            p_s[(wid * 16 + lg * 4 + j) * 136 + src] = f2bf(sacc[n][j]);
    }
    if (lr == 0) {
#pragma unroll
        for (int j = 0; j < 4; j++) z_s[wid * 16 + lg * 4 + j] = z[j];
    }
    bar_lgkm();

    // ---- O^T[dk][dst] = vt @ p^T ----
    f32x4 oacc[4];
#pragma unroll
    for (int n = 0; n < 4; n++) oacc[n] = f32x4{0.f, 0.f, 0.f, 0.f};
#pragma unroll
    for (int kk = 0; kk < 128; kk += 32) {
        int dkr = wid * 16 + lr;
        int g = ((kk >> 3) + lg) ^ (dkr >> 3);
        short8 a = *(const short8*)&vt_s[dkr * 128 + g * 8];
#pragma unroll
        for (int n = 0; n < 4; n++) {
            short8 bf = *(const short8*)&p_s[(n * 16 + lr) * 136 + kk + lg * 8];
            oacc[n] = __builtin_amdgcn_mfma_f32_16x16x32_bf16(a, bf, oacc[n], 0, 0, 0);
        }
    }
#pragma unroll
    for (int n = 0; n < 4; n++) {
        int dl = n * 16 + lr;
        float zz = z_s[dl];
#pragma unroll
        for (int j = 0; j < 4; j++) {
            int dk = wid * 16 + lg * 4 + j;
            O[qbase + (long)dl * RS + dk] = f2bf(oacc[n][j] / zz);
        }
    }
}

// ---------------------------------------------------------------------------
// Generator GEMM, 32x32x16 MFMA, raw barriers, fp16 logits out (halves write).
// 256 thr = 4 waves (2x2), wave tile 64x64, block 128x128. XCD swizzle.
// ---------------------------------------------------------------------------
__global__ __launch_bounds__(256) void gen32_k(
    const short* __restrict__ A, const short* __restrict__ Bt,
    const float* __restrict__ bias, short* __restrict__ Ch, int N, int K)
{
    constexpr int PITCH = 72;
    constexpr int ACH = 4, BCH = 4;    // 128*64/2048
    __shared__ short As[2][128 * PITCH];
    __shared__ short Bs[2][128 * PITCH];

    int bx = blockIdx.x, by = blockIdx.y;
    {   // XCD swizzle (grid 250x4 = 1000, 1000 % 8 == 0)
        int nb = gridDim.x * gridDim.y;
        int bid = by * gridDim.x + bx;
        int w = (bid & 7) * (nb >> 3) + (bid >> 3);
        by = w % gridDim.y; bx = w / gridDim.y;
    }
    int tid = threadIdx.x;
    int lane = tid & 63, wid = tid >> 6;
    int wr = wid >> 1, wc = wid & 1;
    int m0 = by * 128, n0 = bx * 128;
    int l31 = lane & 31, l5 = lane >> 5;

    f32x16 acc[2][2];
#pragma unroll
    for (int m = 0; m < 2; m++)
#pragma unroll
        for (int n = 0; n < 2; n++)
#pragma unroll
            for (int r = 0; r < 16; r++) acc[m][n][r] = 0.f;

    short8 qa0[ACH], qa1[ACH], qb0[BCH], qb1[BCH];
    auto stage = [&](int k0, short8 (&qa)[ACH], short8 (&qb)[BCH]) {
#pragma unroll
        for (int i = 0; i < ACH; i++) {
            int lin = tid + i * 256, r = lin >> 3, c8 = lin & 7;
            qa[i] = *(const short8*)&A[(long)(m0 + r) * K + k0 + c8 * 8];
        }
#pragma unroll
        for (int i = 0; i < BCH; i++) {
            int lin = tid + i * 256, r = lin >> 3, c8 = lin & 7;
            qb[i] = *(const short8*)&Bt[(long)(n0 + r) * K + k0 + c8 * 8];
        }
    };
    auto writeT = [&](int buf, short8 (&qa)[ACH], short8 (&qb)[BCH]) {
#pragma unroll
        for (int i = 0; i < ACH; i++) {
            int lin = tid + i * 256, r = lin >> 3, c8 = lin & 7;
            *(short8*)&As[buf][r * PITCH + c8 * 8] = qa[i];
        }
#pragma unroll
        for (int i = 0; i < BCH; i++) {
            int lin = tid + i * 256, r = lin >> 3, c8 = lin & 7;
            *(short8*)&Bs[buf][r * PITCH + c8 * 8] = qb[i];
        }
    };
    auto mfmaStep = [&](int buf) {
#pragma unroll
        for (int kk = 0; kk < 64; kk += 16) {
            short8 a[2], b[2];
#pragma unroll
            for (int m = 0; m < 2; m++)
                a[m] = *(const short8*)&As[buf][(wr * 64 + m * 32 + l31) * PITCH + kk + l5 * 8];
#pragma unroll
            for (int n = 0; n < 2; n++)
                b[n] = *(const short8*)&Bs[buf][(wc * 64 + n * 32 + l31) * PITCH + kk + l5 * 8];
#pragma unroll
            for (int m = 0; m < 2; m++)
#pragma unroll
                for (int n = 0; n < 2; n++)
                    acc[m][n] = __builtin_amdgcn_mfma_f32_32x32x16_bf16(a[m], b[n], acc[m][n], 0, 0, 0);
        }
    };

    const int steps = K >> 6;   // 8
    stage(0, qa0, qb0);
    stage(64, qa1, qb1);
    int st = 0;
    for (;;) {
        writeT(0, qa0, qb0);
        if (st + 2 < steps) stage((st + 2) * 64, qa0, qb0);
        bar_lgkm();
        mfmaStep(0);
        st++; if (st >= steps) break;

        writeT(1, qa1, qb1);
        if (st + 2 < steps) stage((st + 2) * 64, qa1, qb1);
        bar_lgkm();
        mfmaStep(1);
        st++; if (st >= steps) break;
    }

    // epilogue: 32x32 C/D layout col=lane&31, row=(r&3)+8*(r>>2)+4*(lane>>5)
#pragma unroll
    for (int m = 0; m < 2; m++) {
#pragma unroll
        for (int n = 0; n < 2; n++) {
            int col = n0 + wc * 64 + n * 32 + l31;
            float bv = bias[col];
#pragma unroll
            for (int r = 0; r < 16; r++) {
                int row = m0 + wr * 64 + m * 32 + (r & 3) + 8 * (r >> 2) + 4 * l5;
                Ch[(long)row * N + col] = f2h(acc[m][n][r] + bv);
            }
        }
    }
}

// ---------------------------------------------------------------------------
// Row log_softmax over V=32000: fp16 logits in, fp32 out.
// Online max+sum (1 read pass) + write pass.
// ---------------------------------------------------------------------------
__global__ __launch_bounds__(256) void lsm_k(const short* __restrict__ L16,
                                             float* __restrict__ Out)
{
    __shared__ float rm[256], rs[256];
    int row = blockIdx.x, tid = threadIdx.x;
    const short8* x8 = (const short8*)(L16 + (long)row * cV);
    float* o = Out + (long)row * cV;
    constexpr int NV = cV / 8;   // 4000

    float m = -1e30f, s = 0.f;
    for (int i = tid; i < NV; i += 256) {
        short8 v = x8[i];
        float f[8];
#pragma unroll
        for (int j = 0; j < 8; j++) f[j] = h2f(v[j]);
        float cm = f[0];
#pragma unroll
        for (int j = 1; j < 8; j++) cm = fmaxf(cm, f[j]);
        float nm = fmaxf(m, cm);
        float a = 0.f;
#pragma unroll
        for (int j = 0; j < 8; j++) a += __expf(f[j] - nm);
        s = s * __expf(m - nm) + a;
        m = nm;
    }
    rm[tid] = m; rs[tid] = s;
    __syncthreads();
    for (int st = 128; st > 0; st >>= 1) {
        if (tid < st) {
            float m2 = rm[tid + st], s2 = rs[tid + st];
            float nm = fmaxf(rm[tid], m2);
            rs[tid] = rs[tid] * __expf(rm[tid] - nm) + s2 * __expf(m2 - nm);
            rm[tid] = nm;
        }
        __syncthreads();
    }
    float lse = rm[0] + __logf(rs[0]);

    for (int i = tid; i < NV; i += 256) {
        short8 v = x8[i];
        f32x4 o0, o1;
#pragma unroll
        for (int j = 0; j < 4; j++) o0[j] = h2f(v[j]) - lse;
#pragma unroll
        for (int j = 0; j < 4; j++) o1[j] = h2f(v[4 + j]) - lse;
        *(f32x4*)&o[i * 8]     = o0;
        *(f32x4*)&o[i * 8 + 4] = o1;
    }
}

// ---------------------------------------------------------------------------
extern "C" void kernel_launch(void* const* d_in, const int* in_sizes, int n_in,
                              void* d_out, int out_size, void* d_ws, size_t ws_size,
                              hipStream_t stream)
{
    const float* src_emb  = (const float*)d_in[0];
    const float* tgt_emb  = (const float*)d_in[1];
    const float* enc_Wqkv = (const float*)d_in[2];
    const float* enc_Wo   = (const float*)d_in[3];
    const float* enc_ln1  = (const float*)d_in[4];
    const float* enc_W1   = (const float*)d_in[5];
    const float* enc_b1   = (const float*)d_in[6];
    const float* enc_W2   = (const float*)d_in[7];
    const float* enc_b2   = (const float*)d_in[8];
    const float* enc_ln2  = (const float*)d_in[9];
    const float* enc_lnf  = (const float*)d_in[10];
    const float* dec_Wqkv = (const float*)d_in[11];
    const float* dec_Wo   = (const float*)d_in[12];
    const float* dec_ln1  = (const float*)d_in[13];
    const float* dec_cWq  = (const float*)d_in[14];
    const float* dec_cWkv = (const float*)d_in[15];
    const float* dec_cWo  = (const float*)d_in[16];
    const float* dec_ln2  = (const float*)d_in[17];
    const float* dec_W1   = (const float*)d_in[18];
    const float* dec_b1   = (const float*)d_in[19];
    const float* dec_W2   = (const float*)d_in[20];
    const float* dec_b2   = (const float*)d_in[21];
    const float* dec_ln3  = (const float*)d_in[22];
    const float* dec_lnf  = (const float*)d_in[23];
    const float* gen_W    = (const float*)d_in[24];
    const float* gen_b    = (const float*)d_in[25];
    const int* src_tok    = (const int*)d_in[26];
    const int* tgt_tok    = (const int*)d_in[27];
    // edge lists (28..33): fixed structure (full / causal) -> unused

    const long ND = (long)cN * cD;          // 262144
    const long DD = (long)cD * cD;          // 262144
    const long DF = (long)cD * cF;          // 1048576

    // fp32 region
    float* x_e = (float*)d_ws;
    float* x_d = x_e + ND;

    // bf16 region
    short* qkvb  = (short*)(x_d + ND);      // [3][N,D]  q,k,v
    short* ob_bf = qkvb + 3 * ND;           // [N,D] attn out
    short* hb_bf = ob_bf + ND;              // [N,F]
    short* kvc   = hb_bf + (long)cN * cF;   // [4][N,D] cross K/V (l0k,l0v,l1k,l1v)
    short* xn_bf = kvc + 4 * ND;            // [N,D]
    // transposed bf16 weights
    short* wDD  = xn_bf + ND;               // 24 x [D][D]
    short* wDF  = wDD + 24 * DD;            // 4  x [F][D]  (W1 slices)
    short* wFD  = wDF + 4 * DF;             // 4  x [D][F]  (W2 slices)
    short* genT = wFD + 4 * DF;             // [V][D]
    short* lg16 = genT + (long)cD * cV;     // [N][V] fp16 logits

    // DD slice order: 0-5 enc_Wqkv | 6-7 enc_Wo | 8-13 dec_Wqkv | 14-15 dec_Wo
    //                 16-17 dec_cWq | 18-21 dec_cWkv | 22-23 dec_cWo
    {
        TCP p{};
        int i = 0;
        for (int j = 0; j < 6; j++) p.s[i++] = enc_Wqkv + (long)j * DD;
        for (int j = 0; j < 2; j++) p.s[i++] = enc_Wo   + (long)j * DD;
        for (int j = 0; j < 6; j++) p.s[i++] = dec_Wqkv + (long)j * DD;
        for (int j = 0; j < 2; j++) p.s[i++] = dec_Wo   + (long)j * DD;
        for (int j = 0; j < 2; j++) p.s[i++] = dec_cWq  + (long)j * DD;
        for (int j = 0; j < 4; j++) p.s[i++] = dec_cWkv + (long)j * DD;
        for (int j = 0; j < 2; j++) p.s[i++] = dec_cWo  + (long)j * DD;
        tconv_k<<<dim3(cD / 64, cD / 64, 24), 256, 0, stream>>>(p, wDD, cD, cD);
    }
    {
        TCP p{};
        p.s[0] = enc_W1; p.s[1] = enc_W1 + DF; p.s[2] = dec_W1; p.s[3] = dec_W1 + DF;
        tconv_k<<<dim3(cF / 64, cD / 64, 4), 256, 0, stream>>>(p, wDF, cD, cF);
    }
    {
        TCP p{};
        p.s[0] = enc_W2; p.s[1] = enc_W2 + DF; p.s[2] = dec_W2; p.s[3] = dec_W2 + DF;
        tconv_k<<<dim3(cD / 64, cF / 64, 4), 256, 0, stream>>>(p, wFD, cF, cD);
    }
    {
        TCP p{};
        p.s[0] = gen_W;
        tconv_k<<<dim3(cV / 64, cD / 64, 1), 256, 0, stream>>>(p, genT, cD, cV);
    }

    embed_k<<<dim3(cN, 1, 2), 256, 0, stream>>>(src_emb, src_tok, x_e,
                                                tgt_emb, tgt_tok, x_d);

    dim3 gDD(cD / 32, cN / 32);            // 256 blocks, <1,1>
    dim3 gFFN1(cF / 64, cN / 64);          // 256 blocks, <2,2>
    dim3 gAttn(cH, cB, 2);                 // 64 blocks

    // ---- encoder ----
    for (int l = 0; l < cL; l++) {
        gemm_k<1, 1, true><<<dim3(cD / 32, cN / 32, 3), 256, 0, stream>>>(
            nullptr, x_e, enc_ln1 + (long)(2 * l) * cD, enc_ln1 + (long)(2 * l + 1) * cD,
            wDD + (long)(3 * l) * DD, nullptr, nullptr, nullptr, qkvb,
            cD, cD, 0, DD, ND, 0);
        attn_k<<<gAttn, 256, 0, stream>>>(qkvb, qkvb + ND, qkvb + 2 * ND, ob_bf, 0);
        gemm_k<1, 1, false><<<gDD, 256, 0, stream>>>(
            ob_bf, nullptr, nullptr, nullptr, wDD + (long)(6 + l) * DD,
            nullptr, x_e, x_e, nullptr, cD, cD, 0, 0, 0, 0);
        gemm_k<2, 2, true><<<gFFN1, 256, 0, stream>>>(
            nullptr, x_e, enc_ln2 + (long)(2 * l) * cD, enc_ln2 + (long)(2 * l + 1) * cD,
            wDF + (long)l * DF, enc_b1 + (long)l * cF, nullptr, nullptr, hb_bf,
            cF, cD, 1, 0, 0, 0);
        gemm_k<1, 1, false><<<gDD, 256, 0, stream>>>(
            hb_bf, nullptr, nullptr, nullptr, wFD + (long)l * DF,
            enc_b2 + (long)l * cD, x_e, x_e, nullptr, cD, cF, 0, 0, 0, 0);
    }

    // ---- cross K/V for both decoder layers (enc_lnf fused), z=4 ----
    gemm_k<1, 1, true><<<dim3(cD / 32, cN / 32, 4), 256, 0, stream>>>(
        nullptr, x_e, enc_lnf, enc_lnf + cD,
        wDD + 18 * DD, nullptr, nullptr, nullptr, kvc, cD, cD, 0, DD, ND, 0);

    // ---- decoder ----
    for (int l = 0; l < cL; l++) {
        gemm_k<1, 1, true><<<dim3(cD / 32, cN / 32, 3), 256, 0, stream>>>(
            nullptr, x_d, dec_ln1 + (long)(2 * l) * cD, dec_ln1 + (long)(2 * l + 1) * cD,
            wDD + (long)(8 + 3 * l) * DD, nullptr, nullptr, nullptr, qkvb,
            cD, cD, 0, DD, ND, 0);
        attn_k<<<gAttn, 256, 0, stream>>>(qkvb, qkvb + ND, qkvb + 2 * ND, ob_bf, 1);
        gemm_k<1, 1, false><<<gDD, 256, 0, stream>>>(
            ob_bf, nullptr, nullptr, nullptr, wDD + (long)(14 + l) * DD,
            nullptr, x_d, x_d, nullptr, cD, cD, 0, 0, 0, 0);

        gemm_k<1, 1, true><<<gDD, 256, 0, stream>>>(
            nullptr, x_d, dec_ln2 + (long)(2 * l) * cD, dec_ln2 + (long)(2 * l + 1) * cD,
            wDD + (long)(16 + l) * DD, nullptr, nullptr, nullptr, qkvb,
            cD, cD, 0, 0, 0, 0);
        attn_k<<<gAttn, 256, 0, stream>>>(qkvb, kvc + (long)(2 * l) * ND,
                                          kvc + (long)(2 * l + 1) * ND, ob_bf, 0);
        gemm_k<1, 1, false><<<gDD, 256, 0, stream>>>(
            ob_bf, nullptr, nullptr, nullptr, wDD + (long)(22 + l) * DD,
            nullptr, x_d, x_d, nullptr, cD, cD, 0, 0, 0, 0);

        gemm_k<2, 2, true><<<gFFN1, 256, 0, stream>>>(
            nullptr, x_d, dec_ln3 + (long)(2 * l) * cD, dec_ln3 + (long)(2 * l + 1) * cD,
            wDF + (long)(2 + l) * DF, dec_b1 + (long)l * cF, nullptr, nullptr, hb_bf,
            cF, cD, 1, 0, 0, 0);
        gemm_k<1, 1, false><<<gDD, 256, 0, stream>>>(
            hb_bf, nullptr, nullptr, nullptr, wFD + (long)(2 + l) * DF,
            dec_b2 + (long)l * cD, x_d, x_d, nullptr, cD, cF, 0, 0, 0, 0);
    }

    // ---- final LN + generator (fp16 logits) + log_softmax ----
    ln_k<<<cN, 256, 0, stream>>>(x_d, dec_lnf, dec_lnf + cD, xn_bf);
    gen32_k<<<dim3(cV / 128, cN / 128), 256, 0, stream>>>(
        xn_bf, genT, gen_b, lg16, cV, cD);
    lsm_k<<<cN, 256, 0, stream>>>(lg16, (float*)d_out);
}

// Round 8
// 355.484 us; speedup vs baseline: 1.2681x; 1.0042x over previous
//
#include <hip/hip_runtime.h>
#include <cstddef>

// Problem constants (from reference)
constexpr int cB = 4, cS = 128, cD = 512, cH = 8, cDK = 64, cF = 2048, cL = 2, cV = 32000;
constexpr int cN = cB * cS; // 512

typedef __attribute__((ext_vector_type(8)))  short short8;  // 8 x bf16 (MFMA frag)
typedef __attribute__((ext_vector_type(4)))  float f32x4;
typedef __attribute__((ext_vector_type(16))) float f32x16;  // 32x32 MFMA acc

__device__ __forceinline__ short f2bf(float x) {            // RNE fp32->bf16
    unsigned u = __builtin_bit_cast(unsigned, x);
    unsigned r = (u + 0x7fffu + ((u >> 16) & 1u)) >> 16;
    return (short)r;
}
__device__ __forceinline__ short f2h(float x) {             // fp32 -> fp16 bits
    return __builtin_bit_cast(short, (_Float16)x);
}
__device__ __forceinline__ float h2f(short s) {
    return (float)__builtin_bit_cast(_Float16, s);
}

// Raw barrier: waits LDS ops only (lgkmcnt). Global loads stay IN FLIGHT
// across the barrier (unlike __syncthreads, which drains vmcnt(0) and
// kills the prefetch queue every K-step).
__device__ __forceinline__ void bar_lgkm() {
    asm volatile("s_waitcnt lgkmcnt(0)" ::: "memory");
    __builtin_amdgcn_s_barrier();
    asm volatile("" ::: "memory");
}

// ---------------------------------------------------------------------------
// Embedding + positional encoding, both streams in one launch (z = 0/1)
// ---------------------------------------------------------------------------
__global__ __launch_bounds__(256) void embed_k(const float* __restrict__ e0,
                                               const int* __restrict__ t0,
                                               float* __restrict__ X0,
                                               const float* __restrict__ e1,
                                               const int* __restrict__ t1,
                                               float* __restrict__ X1)
{
    const float* emb = blockIdx.z ? e1 : e0;
    const int* tok   = blockIdx.z ? t1 : t0;
    float* X         = blockIdx.z ? X1 : X0;
    int n = blockIdx.x;
    int tid = threadIdx.x;
    int t = tok[n];
    int pos = n & (cS - 1);
    const float scale = 22.62741699796952f; // sqrt(512)
    for (int d = tid; d < cD; d += 256) {
        int i2 = d & ~1;
        float div = expf(-9.210340371976184f * (float)i2 / (float)cD);
        float arg = (float)pos * div;
        float p = (d & 1) ? cosf(arg) : sinf(arg);
        X[(long)n * cD + d] = emb[(long)t * cD + d] * scale + p;
    }
}

// ---------------------------------------------------------------------------
// LayerNorm -> bf16 (used once, before the generator GEMM)
// ---------------------------------------------------------------------------
__global__ __launch_bounds__(256) void ln_k(const float* __restrict__ X,
                                            const float* __restrict__ g,
                                            const float* __restrict__ bta,
                                            short* __restrict__ Yb)
{
    __shared__ float red[256];
    int row = blockIdx.x, tid = threadIdx.x;
    const float* x = X + (long)row * cD;
    float v0 = x[tid], v1 = x[tid + 256];

    red[tid] = v0 + v1;
    __syncthreads();
    for (int st = 128; st > 0; st >>= 1) { if (tid < st) red[tid] += red[tid + st]; __syncthreads(); }
    float mu = red[0] * (1.0f / (float)cD);
    __syncthreads();

    float d0 = v0 - mu, d1 = v1 - mu;
    red[tid] = d0 * d0 + d1 * d1;
    __syncthreads();
    for (int st = 128; st > 0; st >>= 1) { if (tid < st) red[tid] += red[tid + st]; __syncthreads(); }
    float var = red[0] * (1.0f / (float)cD);
    float rs = rsqrtf(var + 1e-5f);

    Yb[(long)row * cD + tid]       = f2bf(g[tid]       * d0 * rs + bta[tid]);
    Yb[(long)row * cD + tid + 256] = f2bf(g[tid + 256] * d1 * rs + bta[tid + 256]);
}

// ---------------------------------------------------------------------------
// Batched transpose-convert: z slices fp32 [K][N] -> bf16 [N][K] contiguous.
// ---------------------------------------------------------------------------
struct TCP { const float* s[24]; };

__global__ __launch_bounds__(256) void tconv_k(TCP ptrs, short* __restrict__ dst,
                                               int K, int N)
{
    __shared__ float t[64][65];
    const float* s = ptrs.s[blockIdx.z];
    short* d = dst + (long)blockIdx.z * K * N;
    int k0 = blockIdx.y * 64, n0 = blockIdx.x * 64;
    int tid = threadIdx.x;
    const f32x4* s4 = (const f32x4*)s;
#pragma unroll
    for (int i = 0; i < 4; i++) {
        int lin = tid + i * 256;
        int r = lin >> 4, c4 = lin & 15;
        f32x4 v = s4[(long)(k0 + r) * (N >> 2) + (n0 >> 2) + c4];
        t[r][c4 * 4 + 0] = v[0]; t[r][c4 * 4 + 1] = v[1];
        t[r][c4 * 4 + 2] = v[2]; t[r][c4 * 4 + 3] = v[3];
    }
    __syncthreads();
#pragma unroll
    for (int i = 0; i < 2; i++) {
        int lin = tid + i * 256;
        int r = lin >> 3, c8 = lin & 7;
        short8 o;
#pragma unroll
        for (int j = 0; j < 8; j++) o[j] = f2bf(t[c8 * 8 + j][r]);
        *(short8*)&d[(long)(n0 + r) * K + k0 + c8 * 8] = o;
    }
}

// ---------------------------------------------------------------------------
// 8-wave split-K bf16 MFMA GEMM, depth-2 register prefetch, raw lgkm barriers.
//   C = act(LN?(A) @ B + bias) + res
// 512 threads = 8 waves: wave-group grp = wid>>2 owns one K-half; quad 2x2
// tiles the (MR*32)x(NR*32) block output. Combined [*][128] tile per step
// (cols 0-63 = half0 chunk, 64-127 = half1) -> steps = K/128.
// End: grp1 acc added to grp0 via LDS; grp0 does epilogue.
// ---------------------------------------------------------------------------
template <int MR, int NR, bool LNF>
__global__ __launch_bounds__(512) void gemm8_k(
    const short* __restrict__ Abf, const float* __restrict__ Af,
    const float* __restrict__ lng, const float* __restrict__ lnb,
    const short* __restrict__ Bt,
    const float* __restrict__ bias, const float* __restrict__ res,
    float* __restrict__ C, short* __restrict__ Cb,
    int N, int K, int relu, long btStride, long cStride)
{
    constexpr int BM = MR * 32, BN = NR * 32, PITCH = 136; // 128 + 8
    constexpr int ACH = (BM * 128) / (8 * 512);
    constexpr int BCH = (BN * 128) / (8 * 512);
    static_assert(ACH >= 1 && BCH >= 1, "tile too small");
    __shared__ short As[2][BM * PITCH];
    __shared__ short Bs[2][BN * PITCH];
    __shared__ float red[4][64][MR * NR * 4];
    __shared__ float mu_s[BM], rs_s[BM];
    __shared__ float gb_s[2][LNF ? 512 : 8];

    const short* Bm = Bt + (long)blockIdx.z * btStride;
    int tid = threadIdx.x;
    int lane = tid & 63, wid = tid >> 6;
    int grp = wid >> 2, quad = wid & 3;
    int wr = quad >> 1, wc = quad & 1;
    int m0 = blockIdx.y * BM, n0 = blockIdx.x * BN;
    int lrow = lane & 15, koff = (lane >> 4) * 8;
    const int Kh = K >> 1;

    if constexpr (LNF) {   // per-row LN stats over K (==512 at LNF sites)
        constexpr int TPR = 512 / BM;
        int r = tid / TPR, sub = tid % TPR;
        const f32x4* row4 = (const f32x4*)(Af + (long)(m0 + r) * K);
        float s = 0.f, s2 = 0.f;
        for (int i = sub; i < (K >> 2); i += TPR) {
            f32x4 v = row4[i];
            s  += v[0] + v[1] + v[2] + v[3];
            s2 += v[0] * v[0] + v[1] * v[1] + v[2] * v[2] + v[3] * v[3];
        }
#pragma unroll
        for (int o = TPR >> 1; o > 0; o >>= 1) {
            s += __shfl_xor(s, o); s2 += __shfl_xor(s2, o);
        }
        if (sub == 0) {
            float mu = s / (float)K;
            float var = s2 / (float)K - mu * mu;
            mu_s[r] = mu; rs_s[r] = rsqrtf(var + 1e-5f);
        }
        if (tid < 512) { gb_s[0][tid] = lng[tid]; gb_s[1][tid] = lnb[tid]; }
        bar_lgkm();
    }

    f32x4 acc[MR][NR];
#pragma unroll
    for (int m = 0; m < MR; m++)
#pragma unroll
        for (int n = 0; n < NR; n++) acc[m][n] = f32x4{0.f, 0.f, 0.f, 0.f};

    short8 qa0[ACH], qa1[ACH], qb0[BCH], qb1[BCH];

    auto stage = [&](int step, short8 (&qa)[ACH], short8 (&qb)[BCH]) {
#pragma unroll
        for (int i = 0; i < ACH; i++) {
            int lin = tid + i * 512, r = lin >> 4, c8 = lin & 15;
            int kg = (c8 < 8) ? (step * 64 + c8 * 8) : (Kh + step * 64 + (c8 - 8) * 8);
            if constexpr (LNF) {
                const f32x4* p = (const f32x4*)(Af + (long)(m0 + r) * K + kg);
                f32x4 f0 = p[0], f1 = p[1];
                float mu = mu_s[r], rs = rs_s[r];
                short8 o;
#pragma unroll
                for (int j = 0; j < 4; j++)
                    o[j] = f2bf((f0[j] - mu) * rs * gb_s[0][kg + j] + gb_s[1][kg + j]);
#pragma unroll
                for (int j = 0; j < 4; j++)
                    o[4 + j] = f2bf((f1[j] - mu) * rs * gb_s[0][kg + 4 + j] + gb_s[1][kg + 4 + j]);
                qa[i] = o;
            } else {
                qa[i] = *(const short8*)&Abf[(long)(m0 + r) * K + kg];
            }
        }
#pragma unroll
        for (int i = 0; i < BCH; i++) {
            int lin = tid + i * 512, r = lin >> 4, c8 = lin & 15;
            int kg = (c8 < 8) ? (step * 64 + c8 * 8) : (Kh + step * 64 + (c8 - 8) * 8);
            qb[i] = *(const short8*)&Bm[(long)(n0 + r) * K + kg];
        }
    };
    auto writeT = [&](int buf, short8 (&qa)[ACH], short8 (&qb)[BCH]) {
#pragma unroll
        for (int i = 0; i < ACH; i++) {
            int lin = tid + i * 512, r = lin >> 4, c8 = lin & 15;
            *(short8*)&As[buf][r * PITCH + c8 * 8] = qa[i];
        }
#pragma unroll
        for (int i = 0; i < BCH; i++) {
            int lin = tid + i * 512, r = lin >> 4, c8 = lin & 15;
            *(short8*)&Bs[buf][r * PITCH + c8 * 8] = qb[i];
        }
    };
    auto mfmaStep = [&](int buf) {
#pragma unroll
        for (int kk2 = 0; kk2 < 2; kk2++) {
            int kk = grp * 64 + kk2 * 32;
            short8 a[MR], b[NR];
#pragma unroll
            for (int m = 0; m < MR; m++)
                a[m] = *(const short8*)&As[buf][(wr * MR * 16 + m * 16 + lrow) * PITCH + kk + koff];
#pragma unroll
            for (int n = 0; n < NR; n++)
                b[n] = *(const short8*)&Bs[buf][(wc * NR * 16 + n * 16 + lrow) * PITCH + kk + koff];
#pragma unroll
            for (int m = 0; m < MR; m++)
#pragma unroll
                for (int n = 0; n < NR; n++)
                    acc[m][n] = __builtin_amdgcn_mfma_f32_16x16x32_bf16(a[m], b[n], acc[m][n], 0, 0, 0);
        }
    };

    const int steps = K >> 7;   // K / 128
    stage(0, qa0, qb0);
    if (steps > 1) stage(1, qa1, qb1);

    int st = 0;
    for (;;) {
        writeT(0, qa0, qb0);
        if (st + 2 < steps) stage(st + 2, qa0, qb0);
        bar_lgkm();                          // lgkm only: prefetch survives
        mfmaStep(0);
        st++; if (st >= steps) break;

        writeT(1, qa1, qb1);
        if (st + 2 < steps) stage(st + 2, qa1, qb1);
        bar_lgkm();
        mfmaStep(1);
        st++; if (st >= steps) break;
    }

    // cross-group reduction: grp1 -> LDS, grp0 adds + epilogue
    __syncthreads();
    if (grp == 1) {
#pragma unroll
        for (int m = 0; m < MR; m++)
#pragma unroll
            for (int n = 0; n < NR; n++)
#pragma unroll
                for (int j = 0; j < 4; j++)
                    red[quad][lane][(m * NR + n) * 4 + j] = acc[m][n][j];
    }
    __syncthreads();
    if (grp == 0) {
#pragma unroll
        for (int m = 0; m < MR; m++) {
            int rbase = m0 + wr * MR * 16 + m * 16 + (lane >> 4) * 4;
#pragma unroll
            for (int n = 0; n < NR; n++) {
                int col = n0 + wc * NR * 16 + n * 16 + (lane & 15);
                float bv = bias ? bias[col] : 0.f;
#pragma unroll
                for (int j = 0; j < 4; j++) {
                    long row = rbase + j;
                    float v = acc[m][n][j] + red[quad][lane][(m * NR + n) * 4 + j] + bv;
                    if (res)  v += res[row * N + col];
                    if (relu) v = fmaxf(v, 0.f);
                    long off = row * N + col + (long)blockIdx.z * cStride;
                    if (C)  C[off] = v;
                    if (Cb) Cb[off] = f2bf(v);
                }
            }
        }
    }
}

// ---------------------------------------------------------------------------
// MFMA attention: block = (head, batch, dst-half of 64). 256 threads, 4 waves.
// q,k,v,o bf16 [token][H*DK]. Exact reference math:
//   s = exp(clip(q.k/8, +-10)); o = sum(s*v)/sum(s); causal masks src>dst.
// ---------------------------------------------------------------------------
__global__ __launch_bounds__(256) void attn_k(const short* __restrict__ Q,
                                              const short* __restrict__ Km,
                                              const short* __restrict__ Vm,
                                              short* __restrict__ O, int causal)
{
    __shared__ short q_s[64 * 72];     // [dst][dk]  pitch 72
    __shared__ short k_s[128 * 72];    // [src][dk]  pitch 72
    __shared__ short vt_s[64 * 128];   // [dk][src]  granule-swizzled, pitch 128
    __shared__ short p_s[64 * 136];    // [dst][src] pitch 136
    __shared__ float z_s[64];

    int tid = threadIdx.x, lane = tid & 63, wid = tid >> 6;
    int lr = lane & 15, lg = lane >> 4;
    int h = blockIdx.x, b = blockIdx.y, dstBase = blockIdx.z * 64;
    const int RS = cH * cDK; // 512
    long qbase = ((long)b * cS + dstBase) * RS + h * cDK;
    long kbase = ((long)b * cS) * RS + h * cDK;

#pragma unroll
    for (int i = 0; i < 2; i++) {
        int lin = tid + i * 256, t = lin >> 3, c8 = lin & 7;
        *(short8*)&q_s[t * 72 + c8 * 8] = *(const short8*)&Q[qbase + (long)t * RS + c8 * 8];
    }
#pragma unroll
    for (int i = 0; i < 4; i++) {
        int lin = tid + i * 256, t = lin >> 3, c8 = lin & 7;
        *(short8*)&k_s[t * 72 + c8 * 8] = *(const short8*)&Km[kbase + (long)t * RS + c8 * 8];
    }
#pragma unroll
    for (int i = 0; i < 4; i++) {
        int lin = tid + i * 256, src = lin >> 3, c8 = lin & 7;
        short8 v = *(const short8*)&Vm[kbase + (long)src * RS + c8 * 8];
#pragma unroll
        for (int j = 0; j < 8; j++) {
            int dk = c8 * 8 + j;
            int g = (src >> 3) ^ (dk >> 3);
            vt_s[dk * 128 + g * 8 + (src & 7)] = v[j];
        }
    }
    bar_lgkm();

    // ---- S = q @ k^T : wave computes 16 dst rows x 128 src ----
    f32x4 sacc[8];
#pragma unroll
    for (int n = 0; n < 8; n++) sacc[n] = f32x4{0.f, 0.f, 0.f, 0.f};
#pragma unroll
    for (int kk = 0; kk < 64; kk += 32) {
        short8 a = *(const short8*)&q_s[(wid * 16 + lr) * 72 + kk + lg * 8];
#pragma unroll
        for (int n = 0; n < 8; n++) {
            short8 bf = *(const short8*)&k_s[(n * 16 + lr) * 72 + kk + lg * 8];
            sacc[n] = __builtin_amdgcn_mfma_f32_16x16x32_bf16(a, bf, sacc[n], 0, 0, 0);
        }
    }
    float z[4] = {0.f, 0.f, 0.f, 0.f};
#pragma unroll
    for (int n = 0; n < 8; n++) {
        int src = n * 16 + lr;
#pragma unroll
        for (int j = 0; j < 4; j++) {
            int dst = dstBase + wid * 16 + lg * 4 + j;
            float s = sacc[n][j] * 0.125f;
            s = __expf(fminf(fmaxf(s, -10.f), 10.f));
            if (causal && src > dst) s = 0.f;
            sacc[n][j] = s;
            z[j] += s;
        }
    }
#pragma unroll
    for (int j = 0; j < 4; j++) {
        z[j] += __shfl_xor(z[j], 1); z[j] += __shfl_xor(z[j], 2);
        z[j] += __shfl_xor(z[j], 4); z[j] += __shfl_xor(z[j], 8);
    }
#pragma unroll
    for (int n = 0; n < 8; n++) {
        int src = n * 16 + lr;
#pragma unroll
        for (int j = 0; j < 4; j++)
            p_s[(wid * 16 + lg * 4 + j) * 136 + src] = f2bf(sacc[n][j]);
    }
    if (lr == 0) {
#pragma unroll
        for (int j = 0; j < 4; j++) z_s[wid * 16 + lg * 4 + j] = z[j];
    }
    bar_lgkm();

    // ---- O^T[dk][dst] = vt @ p^T ----
    f32x4 oacc[4];
#pragma unroll
    for (int n = 0; n < 4; n++) oacc[n] = f32x4{0.f, 0.f, 0.f, 0.f};
#pragma unroll
    for (int kk = 0; kk < 128; kk += 32) {
        int dkr = wid * 16 + lr;
        int g = ((kk >> 3) + lg) ^ (dkr >> 3);
        short8 a = *(const short8*)&vt_s[dkr * 128 + g * 8];
#pragma unroll
        for (int n = 0; n < 4; n++) {
            short8 bf = *(const short8*)&p_s[(n * 16 + lr) * 136 + kk + lg * 8];
            oacc[n] = __builtin_amdgcn_mfma_f32_16x16x32_bf16(a, bf, oacc[n], 0, 0, 0);
        }
    }
#pragma unroll
    for (int n = 0; n < 4; n++) {
        int dl = n * 16 + lr;
        float zz = z_s[dl];
#pragma unroll
        for (int j = 0; j < 4; j++) {
            int dk = wid * 16 + lg * 4 + j;
            O[qbase + (long)dl * RS + dk] = f2bf(oacc[n][j] / zz);
        }
    }
}

// ---------------------------------------------------------------------------
// Generator GEMM, 32x32x16 MFMA, BK=32 (LDS 40 KB -> 3-4 blocks/CU for TLP),
// raw barriers, fp16 logits out. 256 thr = 4 waves (2x2), wave tile 64x64,
// block 128x128. XCD swizzle.
// ---------------------------------------------------------------------------
__global__ __launch_bounds__(256) void gen32_k(
    const short* __restrict__ A, const short* __restrict__ Bt,
    const float* __restrict__ bias, short* __restrict__ Ch, int N, int K)
{
    constexpr int PITCH = 40;          // 32 + 8
    constexpr int ACH = 2, BCH = 2;    // 128*32/(8*256)
    __shared__ short As[2][128 * PITCH];
    __shared__ short Bs[2][128 * PITCH];

    int bx = blockIdx.x, by = blockIdx.y;
    {   // XCD swizzle (grid 250x4 = 1000, 1000 % 8 == 0)
        int nb = gridDim.x * gridDim.y;
        int bid = by * gridDim.x + bx;
        int w = (bid & 7) * (nb >> 3) + (bid >> 3);
        by = w % gridDim.y; bx = w / gridDim.y;
    }
    int tid = threadIdx.x;
    int lane = tid & 63, wid = tid >> 6;
    int wr = wid >> 1, wc = wid & 1;
    int m0 = by * 128, n0 = bx * 128;
    int l31 = lane & 31, l5 = lane >> 5;

    f32x16 acc[2][2];
#pragma unroll
    for (int m = 0; m < 2; m++)
#pragma unroll
        for (int n = 0; n < 2; n++)
#pragma unroll
            for (int r = 0; r < 16; r++) acc[m][n][r] = 0.f;

    short8 qa0[ACH], qa1[ACH], qb0[BCH], qb1[BCH];
    auto stage = [&](int k0, short8 (&qa)[ACH], short8 (&qb)[BCH]) {
#pragma unroll
        for (int i = 0; i < ACH; i++) {
            int lin = tid + i * 256, r = lin >> 2, c8 = lin & 3;
            qa[i] = *(const short8*)&A[(long)(m0 + r) * K + k0 + c8 * 8];
        }
#pragma unroll
        for (int i = 0; i < BCH; i++) {
            int lin = tid + i * 256, r = lin >> 2, c8 = lin & 3;
            qb[i] = *(const short8*)&Bt[(long)(n0 + r) * K + k0 + c8 * 8];
        }
    };
    auto writeT = [&](int buf, short8 (&qa)[ACH], short8 (&qb)[BCH]) {
#pragma unroll
        for (int i = 0; i < ACH; i++) {
            int lin = tid + i * 256, r = lin >> 2, c8 = lin & 3;
            *(short8*)&As[buf][r * PITCH + c8 * 8] = qa[i];
        }
#pragma unroll
        for (int i = 0; i < BCH; i++) {
            int lin = tid + i * 256, r = lin >> 2, c8 = lin & 3;
            *(short8*)&Bs[buf][r * PITCH + c8 * 8] = qb[i];
        }
    };
    auto mfmaStep = [&](int buf) {
#pragma unroll
        for (int kk = 0; kk < 32; kk += 16) {
            short8 a[2], b[2];
#pragma unroll
            for (int m = 0; m < 2; m++)
                a[m] = *(const short8*)&As[buf][(wr * 64 + m * 32 + l31) * PITCH + kk + l5 * 8];
#pragma unroll
            for (int n = 0; n < 2; n++)
                b[n] = *(const short8*)&Bs[buf][(wc * 64 + n * 32 + l31) * PITCH + kk + l5 * 8];
#pragma unroll
            for (int m = 0; m < 2; m++)
#pragma unroll
                for (int n = 0; n < 2; n++)
                    acc[m][n] = __builtin_amdgcn_mfma_f32_32x32x16_bf16(a[m], b[n], acc[m][n], 0, 0, 0);
        }
    };

    const int steps = K >> 5;   // 16
    stage(0, qa0, qb0);
    stage(32, qa1, qb1);
    int st = 0;
    for (;;) {
        writeT(0, qa0, qb0);
        if (st + 2 < steps) stage((st + 2) * 32, qa0, qb0);
        bar_lgkm();
        mfmaStep(0);
        st++; if (st >= steps) break;

        writeT(1, qa1, qb1);
        if (st + 2 < steps) stage((st + 2) * 32, qa1, qb1);
        bar_lgkm();
        mfmaStep(1);
        st++; if (st >= steps) break;
    }

    // epilogue: 32x32 C/D layout col=lane&31, row=(r&3)+8*(r>>2)+4*(lane>>5)
#pragma unroll
    for (int m = 0; m < 2; m++) {
#pragma unroll
        for (int n = 0; n < 2; n++) {
            int col = n0 + wc * 64 + n * 32 + l31;
            float bv = bias[col];
#pragma unroll
            for (int r = 0; r < 16; r++) {
                int row = m0 + wr * 64 + m * 32 + (r & 3) + 8 * (r >> 2) + 4 * l5;
                Ch[(long)row * N + col] = f2h(acc[m][n][r] + bv);
            }
        }
    }
}

// ---------------------------------------------------------------------------
// Row log_softmax over V=32000: fp16 logits in, fp32 out.
// Online max+sum (1 read pass) + write pass.
// ---------------------------------------------------------------------------
__global__ __launch_bounds__(256) void lsm_k(const short* __restrict__ L16,
                                             float* __restrict__ Out)
{
    __shared__ float rm[256], rs[256];
    int row = blockIdx.x, tid = threadIdx.x;
    const short8* x8 = (const short8*)(L16 + (long)row * cV);
    float* o = Out + (long)row * cV;
    constexpr int NV = cV / 8;   // 4000

    float m = -1e30f, s = 0.f;
    for (int i = tid; i < NV; i += 256) {
        short8 v = x8[i];
        float f[8];
#pragma unroll
        for (int j = 0; j < 8; j++) f[j] = h2f(v[j]);
        float cm = f[0];
#pragma unroll
        for (int j = 1; j < 8; j++) cm = fmaxf(cm, f[j]);
        float nm = fmaxf(m, cm);
        float a = 0.f;
#pragma unroll
        for (int j = 0; j < 8; j++) a += __expf(f[j] - nm);
        s = s * __expf(m - nm) + a;
        m = nm;
    }
    rm[tid] = m; rs[tid] = s;
    __syncthreads();
    for (int st = 128; st > 0; st >>= 1) {
        if (tid < st) {
            float m2 = rm[tid + st], s2 = rs[tid + st];
            float nm = fmaxf(rm[tid], m2);
            rs[tid] = rs[tid] * __expf(rm[tid] - nm) + s2 * __expf(m2 - nm);
            rm[tid] = nm;
        }
        __syncthreads();
    }
    float lse = rm[0] + __logf(rs[0]);

    for (int i = tid; i < NV; i += 256) {
        short8 v = x8[i];
        f32x4 o0, o1;
#pragma unroll
        for (int j = 0; j < 4; j++) o0[j] = h2f(v[j]) - lse;
#pragma unroll
        for (int j = 0; j < 4; j++) o1[j] = h2f(v[4 + j]) - lse;
        *(f32x4*)&o[i * 8]     = o0;
        *(f32x4*)&o[i * 8 + 4] = o1;
    }
}

// ---------------------------------------------------------------------------
extern "C" void kernel_launch(void* const* d_in, const int* in_sizes, int n_in,
                              void* d_out, int out_size, void* d_ws, size_t ws_size,
                              hipStream_t stream)
{
    const float* src_emb  = (const float*)d_in[0];
    const float* tgt_emb  = (const float*)d_in[1];
    const float* enc_Wqkv = (const float*)d_in[2];
    const float* enc_Wo   = (const float*)d_in[3];
    const float* enc_ln1  = (const float*)d_in[4];
    const float* enc_W1   = (const float*)d_in[5];
    const float* enc_b1   = (const float*)d_in[6];
    const float* enc_W2   = (const float*)d_in[7];
    const float* enc_b2   = (const float*)d_in[8];
    const float* enc_ln2  = (const float*)d_in[9];
    const float* enc_lnf  = (const float*)d_in[10];
    const float* dec_Wqkv = (const float*)d_in[11];
    const float* dec_Wo   = (const float*)d_in[12];
    const float* dec_ln1  = (const float*)d_in[13];
    const float* dec_cWq  = (const float*)d_in[14];
    const float* dec_cWkv = (const float*)d_in[15];
    const float* dec_cWo  = (const float*)d_in[16];
    const float* dec_ln2  = (const float*)d_in[17];
    const float* dec_W1   = (const float*)d_in[18];
    const float* dec_b1   = (const float*)d_in[19];
    const float* dec_W2   = (const float*)d_in[20];
    const float* dec_b2   = (const float*)d_in[21];
    const float* dec_ln3  = (const float*)d_in[22];
    const float* dec_lnf  = (const float*)d_in[23];
    const float* gen_W    = (const float*)d_in[24];
    const float* gen_b    = (const float*)d_in[25];
    const int* src_tok    = (const int*)d_in[26];
    const int* tgt_tok    = (const int*)d_in[27];
    // edge lists (28..33): fixed structure (full / causal) -> unused

    const long ND = (long)cN * cD;          // 262144
    const long DD = (long)cD * cD;          // 262144
    const long DF = (long)cD * cF;          // 1048576

    // fp32 region
    float* x_e = (float*)d_ws;
    float* x_d = x_e + ND;

    // bf16 region
    short* qkvb  = (short*)(x_d + ND);      // [3][N,D]  q,k,v
    short* ob_bf = qkvb + 3 * ND;           // [N,D] attn out
    short* hb_bf = ob_bf + ND;              // [N,F]
    short* kvc   = hb_bf + (long)cN * cF;   // [4][N,D] cross K/V (l0k,l0v,l1k,l1v)
    short* xn_bf = kvc + 4 * ND;            // [N,D]
    // transposed bf16 weights
    short* wDD  = xn_bf + ND;               // 24 x [D][D]
    short* wDF  = wDD + 24 * DD;            // 4  x [F][D]  (W1 slices)
    short* wFD  = wDF + 4 * DF;             // 4  x [D][F]  (W2 slices)
    short* genT = wFD + 4 * DF;             // [V][D]
    short* lg16 = genT + (long)cD * cV;     // [N][V] fp16 logits

    // DD slice order: 0-5 enc_Wqkv | 6-7 enc_Wo | 8-13 dec_Wqkv | 14-15 dec_Wo
    //                 16-17 dec_cWq | 18-21 dec_cWkv | 22-23 dec_cWo
    {
        TCP p{};
        int i = 0;
        for (int j = 0; j < 6; j++) p.s[i++] = enc_Wqkv + (long)j * DD;
        for (int j = 0; j < 2; j++) p.s[i++] = enc_Wo   + (long)j * DD;
        for (int j = 0; j < 6; j++) p.s[i++] = dec_Wqkv + (long)j * DD;
        for (int j = 0; j < 2; j++) p.s[i++] = dec_Wo   + (long)j * DD;
        for (int j = 0; j < 2; j++) p.s[i++] = dec_cWq  + (long)j * DD;
        for (int j = 0; j < 4; j++) p.s[i++] = dec_cWkv + (long)j * DD;
        for (int j = 0; j < 2; j++) p.s[i++] = dec_cWo  + (long)j * DD;
        tconv_k<<<dim3(cD / 64, cD / 64, 24), 256, 0, stream>>>(p, wDD, cD, cD);
    }
    {
        TCP p{};
        p.s[0] = enc_W1; p.s[1] = enc_W1 + DF; p.s[2] = dec_W1; p.s[3] = dec_W1 + DF;
        tconv_k<<<dim3(cF / 64, cD / 64, 4), 256, 0, stream>>>(p, wDF, cD, cF);
    }
    {
        TCP p{};
        p.s[0] = enc_W2; p.s[1] = enc_W2 + DF; p.s[2] = dec_W2; p.s[3] = dec_W2 + DF;
        tconv_k<<<dim3(cD / 64, cF / 64, 4), 256, 0, stream>>>(p, wFD, cF, cD);
    }
    {
        TCP p{};
        p.s[0] = gen_W;
        tconv_k<<<dim3(cV / 64, cD / 64, 1), 256, 0, stream>>>(p, genT, cD, cV);
    }

    embed_k<<<dim3(cN, 1, 2), 256, 0, stream>>>(src_emb, src_tok, x_e,
                                                tgt_emb, tgt_tok, x_d);

    dim3 gDD(cD / 32, cN / 32);            // 256 blocks, <1,1>
    dim3 gFFN1(cF / 64, cN / 64);          // 256 blocks, <2,2>
    dim3 gAttn(cH, cB, 2);                 // 64 blocks

    // ---- encoder ----
    for (int l = 0; l < cL; l++) {
        gemm8_k<1, 1, true><<<dim3(cD / 32, cN / 32, 3), 512, 0, stream>>>(
            nullptr, x_e, enc_ln1 + (long)(2 * l) * cD, enc_ln1 + (long)(2 * l + 1) * cD,
            wDD + (long)(3 * l) * DD, nullptr, nullptr, nullptr, qkvb,
            cD, cD, 0, DD, ND);
        attn_k<<<gAttn, 256, 0, stream>>>(qkvb, qkvb + ND, qkvb + 2 * ND, ob_bf, 0);
        gemm8_k<1, 1, false><<<gDD, 512, 0, stream>>>(
            ob_bf, nullptr, nullptr, nullptr, wDD + (long)(6 + l) * DD,
            nullptr, x_e, x_e, nullptr, cD, cD, 0, 0, 0);
        gemm8_k<2, 2, true><<<gFFN1, 512, 0, stream>>>(
            nullptr, x_e, enc_ln2 + (long)(2 * l) * cD, enc_ln2 + (long)(2 * l + 1) * cD,
            wDF + (long)l * DF, enc_b1 + (long)l * cF, nullptr, nullptr, hb_bf,
            cF, cD, 1, 0, 0);
        gemm8_k<1, 1, false><<<gDD, 512, 0, stream>>>(
            hb_bf, nullptr, nullptr, nullptr, wFD + (long)l * DF,
            enc_b2 + (long)l * cD, x_e, x_e, nullptr, cD, cF, 0, 0, 0);
    }

    // ---- cross K/V for both decoder layers (enc_lnf fused), z=4 ----
    gemm8_k<1, 1, true><<<dim3(cD / 32, cN / 32, 4), 512, 0, stream>>>(
        nullptr, x_e, enc_lnf, enc_lnf + cD,
        wDD + 18 * DD, nullptr, nullptr, nullptr, kvc, cD, cD, 0, DD, ND);

    // ---- decoder ----
    for (int l = 0; l < cL; l++) {
        gemm8_k<1, 1, true><<<dim3(cD / 32, cN / 32, 3), 512, 0, stream>>>(
            nullptr, x_d, dec_ln1 + (long)(2 * l) * cD, dec_ln1 + (long)(2 * l + 1) * cD,
            wDD + (long)(8 + 3 * l) * DD, nullptr, nullptr, nullptr, qkvb,
            cD, cD, 0, DD, ND);
        attn_k<<<gAttn, 256, 0, stream>>>(qkvb, qkvb + ND, qkvb + 2 * ND, ob_bf, 1);
        gemm8_k<1, 1, false><<<gDD, 512, 0, stream>>>(
            ob_bf, nullptr, nullptr, nullptr, wDD + (long)(14 + l) * DD,
            nullptr, x_d, x_d, nullptr, cD, cD, 0, 0, 0);

        gemm8_k<1, 1, true><<<gDD, 512, 0, stream>>>(
            nullptr, x_d, dec_ln2 + (long)(2 * l) * cD, dec_ln2 + (long)(2 * l + 1) * cD,
            wDD + (long)(16 + l) * DD, nullptr, nullptr, nullptr, qkvb,
            cD, cD, 0, 0, 0);
        attn_k<<<gAttn, 256, 0, stream>>>(qkvb, kvc + (long)(2 * l) * ND,
                                          kvc + (long)(2 * l + 1) * ND, ob_bf, 0);
        gemm8_k<1, 1, false><<<gDD, 512, 0, stream>>>(
            ob_bf, nullptr, nullptr, nullptr, wDD + (long)(22 + l) * DD,
            nullptr, x_d, x_d, nullptr, cD, cD, 0, 0, 0);

        gemm8_k<2, 2, true><<<gFFN1, 512, 0, stream>>>(
            nullptr, x_d, dec_ln3 + (long)(2 * l) * cD, dec_ln3 + (long)(2 * l + 1) * cD,
            wDF + (long)(2 + l) * DF, dec_b1 + (long)l * cF, nullptr, nullptr, hb_bf,
            cF, cD, 1, 0, 0);
        gemm8_k<1, 1, false><<<gDD, 512, 0, stream>>>(
            hb_bf, nullptr, nullptr, nullptr, wFD + (long)(2 + l) * DF,
            dec_b2 + (long)l * cD, x_d, x_d, nullptr, cD, cF, 0, 0, 0);
    }

    // ---- final LN + generator (fp16 logits) + log_softmax ----
    ln_k<<<cN, 256, 0, stream>>>(x_d, dec_lnf, dec_lnf + cD, xn_bf);
    gen32_k<<<dim3(cV / 128, cN / 128), 256, 0, stream>>>(
        xn_bf, genT, gen_b, lg16, cV, cD);
    lsm_k<<<cN, 256, 0, stream>>>(lg16, (float*)d_out);
}

// Round 9
// 343.019 us; speedup vs baseline: 1.3142x; 1.0363x over previous
//
#include <hip/hip_runtime.h>
#include <cstddef>

// Problem constants (from reference)
constexpr int cB = 4, cS = 128, cD = 512, cH = 8, cDK = 64, cF = 2048, cL = 2, cV = 32000;
constexpr int cN = cB * cS; // 512

typedef __attribute__((ext_vector_type(8)))  short short8;  // 8 x bf16 (MFMA frag)
typedef __attribute__((ext_vector_type(4)))  float f32x4;
typedef __attribute__((ext_vector_type(16))) float f32x16;  // 32x32 MFMA acc

__device__ __forceinline__ short f2bf(float x) {            // RNE fp32->bf16
    unsigned u = __builtin_bit_cast(unsigned, x);
    unsigned r = (u + 0x7fffu + ((u >> 16) & 1u)) >> 16;
    return (short)r;
}
__device__ __forceinline__ short f2h(float x) {             // fp32 -> fp16 bits
    return __builtin_bit_cast(short, (_Float16)x);
}
__device__ __forceinline__ float h2f(short s) {
    return (float)__builtin_bit_cast(_Float16, s);
}

// Raw barrier: waits LDS ops only (lgkmcnt). Global loads stay IN FLIGHT
// across the barrier (unlike __syncthreads, which drains vmcnt(0)).
__device__ __forceinline__ void bar_lgkm() {
    asm volatile("s_waitcnt lgkmcnt(0)" ::: "memory");
    __builtin_amdgcn_s_barrier();
    asm volatile("" ::: "memory");
}

// ---------------------------------------------------------------------------
// Embedding + positional encoding, both streams in one launch (z = 0/1)
// ---------------------------------------------------------------------------
__global__ __launch_bounds__(256) void embed_k(const float* __restrict__ e0,
                                               const int* __restrict__ t0,
                                               float* __restrict__ X0,
                                               const float* __restrict__ e1,
                                               const int* __restrict__ t1,
                                               float* __restrict__ X1)
{
    const float* emb = blockIdx.z ? e1 : e0;
    const int* tok   = blockIdx.z ? t1 : t0;
    float* X         = blockIdx.z ? X1 : X0;
    int n = blockIdx.x;
    int tid = threadIdx.x;
    int t = tok[n];
    int pos = n & (cS - 1);
    const float scale = 22.62741699796952f; // sqrt(512)
    for (int d = tid; d < cD; d += 256) {
        int i2 = d & ~1;
        float div = expf(-9.210340371976184f * (float)i2 / (float)cD);
        float arg = (float)pos * div;
        float p = (d & 1) ? cosf(arg) : sinf(arg);
        X[(long)n * cD + d] = emb[(long)t * cD + d] * scale + p;
    }
}

// ---------------------------------------------------------------------------
// LayerNorm -> bf16 (used once, before the generator GEMM)
// ---------------------------------------------------------------------------
__global__ __launch_bounds__(256) void ln_k(const float* __restrict__ X,
                                            const float* __restrict__ g,
                                            const float* __restrict__ bta,
                                            short* __restrict__ Yb)
{
    __shared__ float red[256];
    int row = blockIdx.x, tid = threadIdx.x;
    const float* x = X + (long)row * cD;
    float v0 = x[tid], v1 = x[tid + 256];

    red[tid] = v0 + v1;
    __syncthreads();
    for (int st = 128; st > 0; st >>= 1) { if (tid < st) red[tid] += red[tid + st]; __syncthreads(); }
    float mu = red[0] * (1.0f / (float)cD);
    __syncthreads();

    float d0 = v0 - mu, d1 = v1 - mu;
    red[tid] = d0 * d0 + d1 * d1;
    __syncthreads();
    for (int st = 128; st > 0; st >>= 1) { if (tid < st) red[tid] += red[tid + st]; __syncthreads(); }
    float var = red[0] * (1.0f / (float)cD);
    float rs = rsqrtf(var + 1e-5f);

    Yb[(long)row * cD + tid]       = f2bf(g[tid]       * d0 * rs + bta[tid]);
    Yb[(long)row * cD + tid + 256] = f2bf(g[tid + 256] * d1 * rs + bta[tid + 256]);
}

// ---------------------------------------------------------------------------
// Batched transpose-convert: z slices fp32 [K][N] -> bf16 [N][K] contiguous.
// ---------------------------------------------------------------------------
struct TCP { const float* s[24]; };

__global__ __launch_bounds__(256) void tconv_k(TCP ptrs, short* __restrict__ dst,
                                               int K, int N)
{
    __shared__ float t[64][65];
    const float* s = ptrs.s[blockIdx.z];
    short* d = dst + (long)blockIdx.z * K * N;
    int k0 = blockIdx.y * 64, n0 = blockIdx.x * 64;
    int tid = threadIdx.x;
    const f32x4* s4 = (const f32x4*)s;
#pragma unroll
    for (int i = 0; i < 4; i++) {
        int lin = tid + i * 256;
        int r = lin >> 4, c4 = lin & 15;
        f32x4 v = s4[(long)(k0 + r) * (N >> 2) + (n0 >> 2) + c4];
        t[r][c4 * 4 + 0] = v[0]; t[r][c4 * 4 + 1] = v[1];
        t[r][c4 * 4 + 2] = v[2]; t[r][c4 * 4 + 3] = v[3];
    }
    __syncthreads();
#pragma unroll
    for (int i = 0; i < 2; i++) {
        int lin = tid + i * 256;
        int r = lin >> 3, c8 = lin & 7;
        short8 o;
#pragma unroll
        for (int j = 0; j < 8; j++) o[j] = f2bf(t[c8 * 8 + j][r]);
        *(short8*)&d[(long)(n0 + r) * K + k0 + c8 * 8] = o;
    }
}

// ---------------------------------------------------------------------------
// 8-wave split-K bf16 MFMA GEMM, depth-2 register prefetch, raw lgkm barriers.
//   C = act(LN?(A) @ B + bias) + res
// zsplit: blocks with z >= zsplit read Af2/lng2/lnb2 (enc/dec stream merge).
// aStride: per-z offset on the bf16 A operand (merged O-projection).
// ---------------------------------------------------------------------------
template <int MR, int NR, bool LNF>
__global__ __launch_bounds__(512) void gemm8_k(
    const short* __restrict__ Abf, const float* __restrict__ Af,
    const float* __restrict__ lng, const float* __restrict__ lnb,
    const float* __restrict__ Af2, const float* __restrict__ lng2,
    const float* __restrict__ lnb2, int zsplit,
    const short* __restrict__ Bt,
    const float* __restrict__ bias, const float* __restrict__ res,
    float* __restrict__ C, short* __restrict__ Cb,
    int N, int K, int relu, long aStride, long btStride, long cStride)
{
    constexpr int BM = MR * 32, BN = NR * 32, PITCH = 136; // 128 + 8
    constexpr int ACH = (BM * 128) / (8 * 512);
    constexpr int BCH = (BN * 128) / (8 * 512);
    static_assert(ACH >= 1 && BCH >= 1, "tile too small");
    __shared__ short As[2][BM * PITCH];
    __shared__ short Bs[2][BN * PITCH];
    __shared__ float red[4][64][MR * NR * 4];
    __shared__ float mu_s[BM], rs_s[BM];
    __shared__ float gb_s[2][LNF ? 512 : 8];

    const int z = blockIdx.z;
    const float* Afz = (LNF && z >= zsplit) ? Af2 : Af;
    const float* gz  = (LNF && z >= zsplit) ? lng2 : lng;
    const float* bz  = (LNF && z >= zsplit) ? lnb2 : lnb;
    const short* Am = Abf ? (Abf + (long)z * aStride) : nullptr;
    const short* Bm = Bt + (long)z * btStride;
    int tid = threadIdx.x;
    int lane = tid & 63, wid = tid >> 6;
    int grp = wid >> 2, quad = wid & 3;
    int wr = quad >> 1, wc = quad & 1;
    int m0 = blockIdx.y * BM, n0 = blockIdx.x * BN;
    int lrow = lane & 15, koff = (lane >> 4) * 8;
    const int Kh = K >> 1;

    if constexpr (LNF) {   // per-row LN stats over K (==512 at LNF sites)
        constexpr int TPR = 512 / BM;
        int r = tid / TPR, sub = tid % TPR;
        const f32x4* row4 = (const f32x4*)(Afz + (long)(m0 + r) * K);
        float s = 0.f, s2 = 0.f;
        for (int i = sub; i < (K >> 2); i += TPR) {
            f32x4 v = row4[i];
            s  += v[0] + v[1] + v[2] + v[3];
            s2 += v[0] * v[0] + v[1] * v[1] + v[2] * v[2] + v[3] * v[3];
        }
#pragma unroll
        for (int o = TPR >> 1; o > 0; o >>= 1) {
            s += __shfl_xor(s, o); s2 += __shfl_xor(s2, o);
        }
        if (sub == 0) {
            float mu = s / (float)K;
            float var = s2 / (float)K - mu * mu;
            mu_s[r] = mu; rs_s[r] = rsqrtf(var + 1e-5f);
        }
        if (tid < 512) { gb_s[0][tid] = gz[tid]; gb_s[1][tid] = bz[tid]; }
        bar_lgkm();
    }

    f32x4 acc[MR][NR];
#pragma unroll
    for (int m = 0; m < MR; m++)
#pragma unroll
        for (int n = 0; n < NR; n++) acc[m][n] = f32x4{0.f, 0.f, 0.f, 0.f};

    short8 qa0[ACH], qa1[ACH], qb0[BCH], qb1[BCH];

    auto stage = [&](int step, short8 (&qa)[ACH], short8 (&qb)[BCH]) {
#pragma unroll
        for (int i = 0; i < ACH; i++) {
            int lin = tid + i * 512, r = lin >> 4, c8 = lin & 15;
            int kg = (c8 < 8) ? (step * 64 + c8 * 8) : (Kh + step * 64 + (c8 - 8) * 8);
            if constexpr (LNF) {
                const f32x4* p = (const f32x4*)(Afz + (long)(m0 + r) * K + kg);
                f32x4 f0 = p[0], f1 = p[1];
                float mu = mu_s[r], rs = rs_s[r];
                short8 o;
#pragma unroll
                for (int j = 0; j < 4; j++)
                    o[j] = f2bf((f0[j] - mu) * rs * gb_s[0][kg + j] + gb_s[1][kg + j]);
#pragma unroll
                for (int j = 0; j < 4; j++)
                    o[4 + j] = f2bf((f1[j] - mu) * rs * gb_s[0][kg + 4 + j] + gb_s[1][kg + 4 + j]);
                qa[i] = o;
            } else {
                qa[i] = *(const short8*)&Am[(long)(m0 + r) * K + kg];
            }
        }
#pragma unroll
        for (int i = 0; i < BCH; i++) {
            int lin = tid + i * 512, r = lin >> 4, c8 = lin & 15;
            int kg = (c8 < 8) ? (step * 64 + c8 * 8) : (Kh + step * 64 + (c8 - 8) * 8);
            qb[i] = *(const short8*)&Bm[(long)(n0 + r) * K + kg];
        }
    };
    auto writeT = [&](int buf, short8 (&qa)[ACH], short8 (&qb)[BCH]) {
#pragma unroll
        for (int i = 0; i < ACH; i++) {
            int lin = tid + i * 512, r = lin >> 4, c8 = lin & 15;
            *(short8*)&As[buf][r * PITCH + c8 * 8] = qa[i];
        }
#pragma unroll
        for (int i = 0; i < BCH; i++) {
            int lin = tid + i * 512, r = lin >> 4, c8 = lin & 15;
            *(short8*)&Bs[buf][r * PITCH + c8 * 8] = qb[i];
        }
    };
    auto mfmaStep = [&](int buf) {
#pragma unroll
        for (int kk2 = 0; kk2 < 2; kk2++) {
            int kk = grp * 64 + kk2 * 32;
            short8 a[MR], b[NR];
#pragma unroll
            for (int m = 0; m < MR; m++)
                a[m] = *(const short8*)&As[buf][(wr * MR * 16 + m * 16 + lrow) * PITCH + kk + koff];
#pragma unroll
            for (int n = 0; n < NR; n++)
                b[n] = *(const short8*)&Bs[buf][(wc * NR * 16 + n * 16 + lrow) * PITCH + kk + koff];
#pragma unroll
            for (int m = 0; m < MR; m++)
#pragma unroll
                for (int n = 0; n < NR; n++)
                    acc[m][n] = __builtin_amdgcn_mfma_f32_16x16x32_bf16(a[m], b[n], acc[m][n], 0, 0, 0);
        }
    };

    const int steps = K >> 7;   // K / 128
    stage(0, qa0, qb0);
    if (steps > 1) stage(1, qa1, qb1);

    int st = 0;
    for (;;) {
        writeT(0, qa0, qb0);
        if (st + 2 < steps) stage(st + 2, qa0, qb0);
        bar_lgkm();                          // lgkm only: prefetch survives
        mfmaStep(0);
        st++; if (st >= steps) break;

        writeT(1, qa1, qb1);
        if (st + 2 < steps) stage(st + 2, qa1, qb1);
        bar_lgkm();
        mfmaStep(1);
        st++; if (st >= steps) break;
    }

    // cross-group reduction: grp1 -> LDS, grp0 adds + epilogue
    __syncthreads();
    if (grp == 1) {
#pragma unroll
        for (int m = 0; m < MR; m++)
#pragma unroll
            for (int n = 0; n < NR; n++)
#pragma unroll
                for (int j = 0; j < 4; j++)
                    red[quad][lane][(m * NR + n) * 4 + j] = acc[m][n][j];
    }
    __syncthreads();
    if (grp == 0) {
#pragma unroll
        for (int m = 0; m < MR; m++) {
            int rbase = m0 + wr * MR * 16 + m * 16 + (lane >> 4) * 4;
#pragma unroll
            for (int n = 0; n < NR; n++) {
                int col = n0 + wc * NR * 16 + n * 16 + (lane & 15);
                float bv = bias ? bias[col] : 0.f;
#pragma unroll
                for (int j = 0; j < 4; j++) {
                    long row = rbase + j;
                    long off = row * N + col + (long)z * cStride;
                    float v = acc[m][n][j] + red[quad][lane][(m * NR + n) * 4 + j] + bv;
                    if (res)  v += res[off];
                    if (relu) v = fmaxf(v, 0.f);
                    if (C)  C[off] = v;
                    if (Cb) Cb[off] = f2bf(v);
                }
            }
        }
    }
}

// ---------------------------------------------------------------------------
// MFMA attention, multi-stream: grid z = (stream<<1) | dstHalf.
// Q/K/V/O base + per-stream strides; causal = (causMask >> stream) & 1.
// q,k,v,o bf16 [token][H*DK]. Exact reference math:
//   s = exp(clip(q.k/8, +-10)); o = sum(s*v)/sum(s); causal masks src>dst.
// ---------------------------------------------------------------------------
__global__ __launch_bounds__(256) void attn_k(const short* __restrict__ Qb,
                                              const short* __restrict__ Kb,
                                              const short* __restrict__ Vb,
                                              short* __restrict__ Ob,
                                              int causMask, long sQKV, long sO)
{
    __shared__ short q_s[64 * 72];     // [dst][dk]  pitch 72
    __shared__ short k_s[128 * 72];    // [src][dk]  pitch 72
    __shared__ short vt_s[64 * 128];   // [dk][src]  granule-swizzled, pitch 128
    __shared__ short p_s[64 * 136];    // [dst][src] pitch 136
    __shared__ float z_s[64];

    int tid = threadIdx.x, lane = tid & 63, wid = tid >> 6;
    int lr = lane & 15, lg = lane >> 4;
    int h = blockIdx.x, b = blockIdx.y;
    int stream = blockIdx.z >> 1, dstBase = (blockIdx.z & 1) * 64;
    int causal = (causMask >> stream) & 1;
    const short* Q = Qb + (long)stream * sQKV;
    const short* Km = Kb + (long)stream * sQKV;
    const short* Vm = Vb + (long)stream * sQKV;
    short* O = Ob + (long)stream * sO;
    const int RS = cH * cDK; // 512
    long qbase = ((long)b * cS + dstBase) * RS + h * cDK;
    long kbase = ((long)b * cS) * RS + h * cDK;

#pragma unroll
    for (int i = 0; i < 2; i++) {
        int lin = tid + i * 256, t = lin >> 3, c8 = lin & 7;
        *(short8*)&q_s[t * 72 + c8 * 8] = *(const short8*)&Q[qbase + (long)t * RS + c8 * 8];
    }
#pragma unroll
    for (int i = 0; i < 4; i++) {
        int lin = tid + i * 256, t = lin >> 3, c8 = lin & 7;
        *(short8*)&k_s[t * 72 + c8 * 8] = *(const short8*)&Km[kbase + (long)t * RS + c8 * 8];
    }
#pragma unroll
    for (int i = 0; i < 4; i++) {
        int lin = tid + i * 256, src = lin >> 3, c8 = lin & 7;
        short8 v = *(const short8*)&Vm[kbase + (long)src * RS + c8 * 8];
#pragma unroll
        for (int j = 0; j < 8; j++) {
            int dk = c8 * 8 + j;
            int g = (src >> 3) ^ (dk >> 3);
            vt_s[dk * 128 + g * 8 + (src & 7)] = v[j];
        }
    }
    bar_lgkm();

    // ---- S = q @ k^T : wave computes 16 dst rows x 128 src ----
    f32x4 sacc[8];
#pragma unroll
    for (int n = 0; n < 8; n++) sacc[n] = f32x4{0.f, 0.f, 0.f, 0.f};
#pragma unroll
    for (int kk = 0; kk < 64; kk += 32) {
        short8 a = *(const short8*)&q_s[(wid * 16 + lr) * 72 + kk + lg * 8];
#pragma unroll
        for (int n = 0; n < 8; n++) {
            short8 bf = *(const short8*)&k_s[(n * 16 + lr) * 72 + kk + lg * 8];
            sacc[n] = __builtin_amdgcn_mfma_f32_16x16x32_bf16(a, bf, sacc[n], 0, 0, 0);
        }
    }
    float z[4] = {0.f, 0.f, 0.f, 0.f};
#pragma unroll
    for (int n = 0; n < 8; n++) {
        int src = n * 16 + lr;
#pragma unroll
        for (int j = 0; j < 4; j++) {
            int dst = dstBase + wid * 16 + lg * 4 + j;
            float s = sacc[n][j] * 0.125f;
            s = __expf(fminf(fmaxf(s, -10.f), 10.f));
            if (causal && src > dst) s = 0.f;
            sacc[n][j] = s;
            z[j] += s;
        }
    }
#pragma unroll
    for (int j = 0; j < 4; j++) {
        z[j] += __shfl_xor(z[j], 1); z[j] += __shfl_xor(z[j], 2);
        z[j] += __shfl_xor(z[j], 4); z[j] += __shfl_xor(z[j], 8);
    }
#pragma unroll
    for (int n = 0; n < 8; n++) {
        int src = n * 16 + lr;
#pragma unroll
        for (int j = 0; j < 4; j++)
            p_s[(wid * 16 + lg * 4 + j) * 136 + src] = f2bf(sacc[n][j]);
    }
    if (lr == 0) {
#pragma unroll
        for (int j = 0; j < 4; j++) z_s[wid * 16 + lg * 4 + j] = z[j];
    }
    bar_lgkm();

    // ---- O^T[dk][dst] = vt @ p^T ----
    f32x4 oacc[4];
#pragma unroll
    for (int n = 0; n < 4; n++) oacc[n] = f32x4{0.f, 0.f, 0.f, 0.f};
#pragma unroll
    for (int kk = 0; kk < 128; kk += 32) {
        int dkr = wid * 16 + lr;
        int g = ((kk >> 3) + lg) ^ (dkr >> 3);
        short8 a = *(const short8*)&vt_s[dkr * 128 + g * 8];
#pragma unroll
        for (int n = 0; n < 4; n++) {
            short8 bf = *(const short8*)&p_s[(n * 16 + lr) * 136 + kk + lg * 8];
            oacc[n] = __builtin_amdgcn_mfma_f32_16x16x32_bf16(a, bf, oacc[n], 0, 0, 0);
        }
    }
#pragma unroll
    for (int n = 0; n < 4; n++) {
        int dl = n * 16 + lr;
        float zz = z_s[dl];
#pragma unroll
        for (int j = 0; j < 4; j++) {
            int dk = wid * 16 + lg * 4 + j;
            O[qbase + (long)dl * RS + dk] = f2bf(oacc[n][j] / zz);
        }
    }
}

// ---------------------------------------------------------------------------
// Generator GEMM, 32x32x16 MFMA, reads gen_W fp32 DIRECTLY (no tconv).
// A bf16 [M][K] (PITCH 72, proven conflict-free b128 reads); B staged fp32
// [k][n] (PITCH 132; frag lanes hit distinct banks, k-groups 2-way = free).
// Single-buffered LDS (52 KB -> 2-3 blocks/CU), depth-2 reg prefetch,
// raw lgkm barriers, fp16 logits out, XCD swizzle. BK=64, 8 steps.
// ---------------------------------------------------------------------------
__global__ __launch_bounds__(256) void gen32_k(
    const short* __restrict__ A, const float* __restrict__ Bw,
    const float* __restrict__ bias, short* __restrict__ Ch, int N, int K)
{
    constexpr int PA = 72, PB = 132;
    __shared__ short As[128 * PA];      // 18.4 KB
    __shared__ float Bsf[64 * PB];      // 33.8 KB

    int bx = blockIdx.x, by = blockIdx.y;
    {   // XCD swizzle (grid 250x4 = 1000, 1000 % 8 == 0)
        int nb = gridDim.x * gridDim.y;
        int bid = by * gridDim.x + bx;
        int w = (bid & 7) * (nb >> 3) + (bid >> 3);
        by = w % gridDim.y; bx = w / gridDim.y;
    }
    int tid = threadIdx.x;
    int lane = tid & 63, wid = tid >> 6;
    int wr = wid >> 1, wc = wid & 1;
    int m0 = by * 128, n0 = bx * 128;
    int l31 = lane & 31, l5 = lane >> 5;

    f32x16 acc[2][2];
#pragma unroll
    for (int m = 0; m < 2; m++)
#pragma unroll
        for (int n = 0; n < 2; n++)
#pragma unroll
            for (int r = 0; r < 16; r++) acc[m][n][r] = 0.f;

    short8 qa0[4], qa1[4];
    f32x4  qb0[8], qb1[8];
    auto stage = [&](int k0, short8 (&qa)[4], f32x4 (&qb)[8]) {
#pragma unroll
        for (int i = 0; i < 4; i++) {                 // A: 128 rows x 64 k bf16
            int lin = tid + i * 256, r = lin >> 3, c8 = lin & 7;
            qa[i] = *(const short8*)&A[(long)(m0 + r) * K + k0 + c8 * 8];
        }
#pragma unroll
        for (int i = 0; i < 8; i++) {                 // B: 64 k-rows x 128 n fp32
            int lin = tid + i * 256, kr = lin >> 5, c4 = lin & 31;
            qb[i] = *(const f32x4*)&Bw[(long)(k0 + kr) * N + n0 + c4 * 4];
        }
    };
    auto writeT = [&](short8 (&qa)[4], f32x4 (&qb)[8]) {
#pragma unroll
        for (int i = 0; i < 4; i++) {
            int lin = tid + i * 256, r = lin >> 3, c8 = lin & 7;
            *(short8*)&As[r * PA + c8 * 8] = qa[i];
        }
#pragma unroll
        for (int i = 0; i < 8; i++) {
            int lin = tid + i * 256, kr = lin >> 5, c4 = lin & 31;
            *(f32x4*)&Bsf[kr * PB + c4 * 4] = qb[i];
        }
    };
    auto mfmaStep = [&]() {
#pragma unroll
        for (int kk = 0; kk < 64; kk += 16) {
            short8 a[2], b[2];
#pragma unroll
            for (int m = 0; m < 2; m++)
                a[m] = *(const short8*)&As[(wr * 64 + m * 32 + l31) * PA + kk + l5 * 8];
#pragma unroll
            for (int n = 0; n < 2; n++) {
                int col = wc * 64 + n * 32 + l31;
#pragma unroll
                for (int j = 0; j < 8; j++)
                    b[n][j] = f2bf(Bsf[(kk + l5 * 8 + j) * PB + col]);
            }
#pragma unroll
            for (int m = 0; m < 2; m++)
#pragma unroll
                for (int n = 0; n < 2; n++)
                    acc[m][n] = __builtin_amdgcn_mfma_f32_32x32x16_bf16(a[m], b[n], acc[m][n], 0, 0, 0);
        }
    };

    const int steps = K >> 6;   // 8
    stage(0, qa0, qb0);
    stage(64, qa1, qb1);
    int st = 0;
    for (;;) {
        if (st) bar_lgkm();                   // prior frag reads done
        writeT(qa0, qb0);
        if (st + 2 < steps) stage((st + 2) * 64, qa0, qb0);
        bar_lgkm();                           // writes visible
        mfmaStep();
        st++; if (st >= steps) break;

        bar_lgkm();
        writeT(qa1, qb1);
        if (st + 2 < steps) stage((st + 2) * 64, qa1, qb1);
        bar_lgkm();
        mfmaStep();
        st++; if (st >= steps) break;
    }

    // epilogue: 32x32 C/D layout col=lane&31, row=(r&3)+8*(r>>2)+4*(lane>>5)
#pragma unroll
    for (int m = 0; m < 2; m++) {
#pragma unroll
        for (int n = 0; n < 2; n++) {
            int col = n0 + wc * 64 + n * 32 + l31;
            float bv = bias[col];
#pragma unroll
            for (int r = 0; r < 16; r++) {
                int row = m0 + wr * 64 + m * 32 + (r & 3) + 8 * (r >> 2) + 4 * l5;
                Ch[(long)row * N + col] = f2h(acc[m][n][r] + bv);
            }
        }
    }
}

// ---------------------------------------------------------------------------
// Row log_softmax over V=32000: fp16 logits in, fp32 out.
// Online max+sum (1 read pass) + write pass.
// ---------------------------------------------------------------------------
__global__ __launch_bounds__(256) void lsm_k(const short* __restrict__ L16,
                                             float* __restrict__ Out)
{
    __shared__ float rm[256], rs[256];
    int row = blockIdx.x, tid = threadIdx.x;
    const short8* x8 = (const short8*)(L16 + (long)row * cV);
    float* o = Out + (long)row * cV;
    constexpr int NV = cV / 8;   // 4000

    float m = -1e30f, s = 0.f;
    for (int i = tid; i < NV; i += 256) {
        short8 v = x8[i];
        float f[8];
#pragma unroll
        for (int j = 0; j < 8; j++) f[j] = h2f(v[j]);
        float cm = f[0];
#pragma unroll
        for (int j = 1; j < 8; j++) cm = fmaxf(cm, f[j]);
        float nm = fmaxf(m, cm);
        float a = 0.f;
#pragma unroll
        for (int j = 0; j < 8; j++) a += __expf(f[j] - nm);
        s = s * __expf(m - nm) + a;
        m = nm;
    }
    rm[tid] = m; rs[tid] = s;
    __syncthreads();
    for (int st = 128; st > 0; st >>= 1) {
        if (tid < st) {
            float m2 = rm[tid + st], s2 = rs[tid + st];
            float nm = fmaxf(rm[tid], m2);
            rs[tid] = rs[tid] * __expf(rm[tid] - nm) + s2 * __expf(m2 - nm);
            rm[tid] = nm;
        }
        __syncthreads();
    }
    float lse = rm[0] + __logf(rs[0]);

    for (int i = tid; i < NV; i += 256) {
        short8 v = x8[i];
        f32x4 o0, o1;
#pragma unroll
        for (int j = 0; j < 4; j++) o0[j] = h2f(v[j]) - lse;
#pragma unroll
        for (int j = 0; j < 4; j++) o1[j] = h2f(v[4 + j]) - lse;
        *(f32x4*)&o[i * 8]     = o0;
        *(f32x4*)&o[i * 8 + 4] = o1;
    }
}

// ---------------------------------------------------------------------------
extern "C" void kernel_launch(void* const* d_in, const int* in_sizes, int n_in,
                              void* d_out, int out_size, void* d_ws, size_t ws_size,
                              hipStream_t stream)
{
    const float* src_emb  = (const float*)d_in[0];
    const float* tgt_emb  = (const float*)d_in[1];
    const float* enc_Wqkv = (const float*)d_in[2];
    const float* enc_Wo   = (const float*)d_in[3];
    const float* enc_ln1  = (const float*)d_in[4];
    const float* enc_W1   = (const float*)d_in[5];
    const float* enc_b1   = (const float*)d_in[6];
    const float* enc_W2   = (const float*)d_in[7];
    const float* enc_b2   = (const float*)d_in[8];
    const float* enc_ln2  = (const float*)d_in[9];
    const float* enc_lnf  = (const float*)d_in[10];
    const float* dec_Wqkv = (const float*)d_in[11];
    const float* dec_Wo   = (const float*)d_in[12];
    const float* dec_ln1  = (const float*)d_in[13];
    const float* dec_cWq  = (const float*)d_in[14];
    const float* dec_cWkv = (const float*)d_in[15];
    const float* dec_cWo  = (const float*)d_in[16];
    const float* dec_ln2  = (const float*)d_in[17];
    const float* dec_W1   = (const float*)d_in[18];
    const float* dec_b1   = (const float*)d_in[19];
    const float* dec_W2   = (const float*)d_in[20];
    const float* dec_b2   = (const float*)d_in[21];
    const float* dec_ln3  = (const float*)d_in[22];
    const float* dec_lnf  = (const float*)d_in[23];
    const float* gen_W    = (const float*)d_in[24];
    const float* gen_b    = (const float*)d_in[25];
    const int* src_tok    = (const int*)d_in[26];
    const int* tgt_tok    = (const int*)d_in[27];
    // edge lists (28..33): fixed structure (full / causal) -> unused

    const long ND = (long)cN * cD;          // 262144
    const long DD = (long)cD * cD;          // 262144
    const long DF = (long)cD * cF;          // 1048576

    // fp32 region (x_e and x_d MUST be adjacent: merged O-proj uses stride ND)
    float* x_e = (float*)d_ws;
    float* x_d = x_e + ND;

    // bf16 region
    short* qkv6  = (short*)(x_d + ND);      // [6][N,D] encQ,encK,encV,decQ,decK,decV
    short* ob2   = qkv6 + 6 * ND;           // [2][N,D] attn out (enc, dec)
    short* hb_bf = ob2 + 2 * ND;            // [N,F]
    short* kvc   = hb_bf + (long)cN * cF;   // [4][N,D] cross K/V (l0k,l0v,l1k,l1v)
    short* xn_bf = kvc + 4 * ND;            // [N,D]
    // transposed bf16 weights
    short* wDD  = xn_bf + ND;               // 24 x [D][D]
    short* wDF  = wDD + 24 * DD;            // 4  x [F][D]  (W1 slices)
    short* wFD  = wDF + 4 * DF;             // 4  x [D][F]  (W2 slices)
    short* lg16 = wFD + 4 * DF;             // [N][V] fp16 logits

    // wDD slice order (strides chosen for merged launches):
    //  0-2 enc_Wqkv l0 | 3-5 dec_Wqkv l0 | 6 enc_Wo l0 | 7 dec_Wo l0
    //  8-10 enc_Wqkv l1 | 11-13 dec_Wqkv l1 | 14 enc_Wo l1 | 15 dec_Wo l1
    //  16-17 dec_cWq | 18-21 dec_cWkv | 22-23 dec_cWo
    {
        TCP p{};
        int i = 0;
        for (int j = 0; j < 3; j++) p.s[i++] = enc_Wqkv + (long)j * DD;
        for (int j = 0; j < 3; j++) p.s[i++] = dec_Wqkv + (long)j * DD;
        p.s[i++] = enc_Wo; p.s[i++] = dec_Wo;
        for (int j = 3; j < 6; j++) p.s[i++] = enc_Wqkv + (long)j * DD;
        for (int j = 3; j < 6; j++) p.s[i++] = dec_Wqkv + (long)j * DD;
        p.s[i++] = enc_Wo + DD; p.s[i++] = dec_Wo + DD;
        for (int j = 0; j < 2; j++) p.s[i++] = dec_cWq  + (long)j * DD;
        for (int j = 0; j < 4; j++) p.s[i++] = dec_cWkv + (long)j * DD;
        for (int j = 0; j < 2; j++) p.s[i++] = dec_cWo  + (long)j * DD;
        tconv_k<<<dim3(cD / 64, cD / 64, 24), 256, 0, stream>>>(p, wDD, cD, cD);
    }
    {
        TCP p{};
        p.s[0] = enc_W1; p.s[1] = enc_W1 + DF; p.s[2] = dec_W1; p.s[3] = dec_W1 + DF;
        tconv_k<<<dim3(cF / 64, cD / 64, 4), 256, 0, stream>>>(p, wDF, cD, cF);
    }
    {
        TCP p{};
        p.s[0] = enc_W2; p.s[1] = enc_W2 + DF; p.s[2] = dec_W2; p.s[3] = dec_W2 + DF;
        tconv_k<<<dim3(cD / 64, cF / 64, 4), 256, 0, stream>>>(p, wFD, cF, cD);
    }

    embed_k<<<dim3(cN, 1, 2), 256, 0, stream>>>(src_emb, src_tok, x_e,
                                                tgt_emb, tgt_tok, x_d);

    dim3 gDD(cD / 32, cN / 32);            // 256 blocks
    dim3 gFFN1(cF / 64, cN / 64);          // 256 blocks, <2,2>

    // ====== merged: enc layer0 self + dec layer0 self (independent) ======
    gemm8_k<1, 1, true><<<dim3(cD / 32, cN / 32, 6), 512, 0, stream>>>(
        nullptr, x_e, enc_ln1, enc_ln1 + cD,
        x_d, dec_ln1, dec_ln1 + cD, 3,
        wDD, nullptr, nullptr, nullptr, qkv6, cD, cD, 0, 0, DD, ND);
    attn_k<<<dim3(cH, cB, 4), 256, 0, stream>>>(
        qkv6, qkv6 + ND, qkv6 + 2 * ND, ob2, 0b10, 3 * ND, ND);
    gemm8_k<1, 1, false><<<dim3(cD / 32, cN / 32, 2), 512, 0, stream>>>(
        ob2, nullptr, nullptr, nullptr, nullptr, nullptr, nullptr, 99,
        wDD + 6 * DD, nullptr, x_e, x_e, nullptr, cD, cD, 0, ND, DD, ND);

    // ====== encoder layer0 FFN ======
    gemm8_k<2, 2, true><<<gFFN1, 512, 0, stream>>>(
        nullptr, x_e, enc_ln2, enc_ln2 + cD, nullptr, nullptr, nullptr, 99,
        wDF, enc_b1, nullptr, nullptr, hb_bf, cF, cD, 1, 0, 0, 0);
    gemm8_k<1, 1, false><<<gDD, 512, 0, stream>>>(
        hb_bf, nullptr, nullptr, nullptr, nullptr, nullptr, nullptr, 99,
        wFD, enc_b2, x_e, x_e, nullptr, cD, cF, 0, 0, 0, 0);

    // ====== encoder layer1 ======
    gemm8_k<1, 1, true><<<dim3(cD / 32, cN / 32, 3), 512, 0, stream>>>(
        nullptr, x_e, enc_ln1 + 2 * cD, enc_ln1 + 3 * cD,
        nullptr, nullptr, nullptr, 99,
        wDD + 8 * DD, nullptr, nullptr, nullptr, qkv6, cD, cD, 0, 0, DD, ND);
    attn_k<<<dim3(cH, cB, 2), 256, 0, stream>>>(
        qkv6, qkv6 + ND, qkv6 + 2 * ND, ob2, 0, 0, 0);
    gemm8_k<1, 1, false><<<gDD, 512, 0, stream>>>(
        ob2, nullptr, nullptr, nullptr, nullptr, nullptr, nullptr, 99,
        wDD + 14 * DD, nullptr, x_e, x_e, nullptr, cD, cD, 0, 0, 0, 0);
    gemm8_k<2, 2, true><<<gFFN1, 512, 0, stream>>>(
        nullptr, x_e, enc_ln2 + 2 * cD, enc_ln2 + 3 * cD,
        nullptr, nullptr, nullptr, 99,
        wDF + DF, enc_b1 + cF, nullptr, nullptr, hb_bf, cF, cD, 1, 0, 0, 0);
    gemm8_k<1, 1, false><<<gDD, 512, 0, stream>>>(
        hb_bf, nullptr, nullptr, nullptr, nullptr, nullptr, nullptr, 99,
        wFD + DF, enc_b2 + cD, x_e, x_e, nullptr, cD, cF, 0, 0, 0, 0);

    // ====== cross K/V for both decoder layers (enc_lnf fused), z=4 ======
    gemm8_k<1, 1, true><<<dim3(cD / 32, cN / 32, 4), 512, 0, stream>>>(
        nullptr, x_e, enc_lnf, enc_lnf + cD, nullptr, nullptr, nullptr, 99,
        wDD + 18 * DD, nullptr, nullptr, nullptr, kvc, cD, cD, 0, 0, DD, ND);

    // ====== decoder layers ======
    for (int l = 0; l < cL; l++) {
        if (l == 1) {   // dec l1 self (l0 self already done in merged phase)
            gemm8_k<1, 1, true><<<dim3(cD / 32, cN / 32, 3), 512, 0, stream>>>(
                nullptr, x_d, dec_ln1 + 2 * cD, dec_ln1 + 3 * cD,
                nullptr, nullptr, nullptr, 99,
                wDD + 11 * DD, nullptr, nullptr, nullptr, qkv6, cD, cD, 0, 0, DD, ND);
            attn_k<<<dim3(cH, cB, 2), 256, 0, stream>>>(
                qkv6, qkv6 + ND, qkv6 + 2 * ND, ob2, 1, 0, 0);
            gemm8_k<1, 1, false><<<gDD, 512, 0, stream>>>(
                ob2, nullptr, nullptr, nullptr, nullptr, nullptr, nullptr, 99,
                wDD + 15 * DD, nullptr, x_d, x_d, nullptr, cD, cD, 0, 0, 0, 0);
        }
        // cross-attention
        gemm8_k<1, 1, true><<<gDD, 512, 0, stream>>>(
            nullptr, x_d, dec_ln2 + (long)(2 * l) * cD, dec_ln2 + (long)(2 * l + 1) * cD,
            nullptr, nullptr, nullptr, 99,
            wDD + (long)(16 + l) * DD, nullptr, nullptr, nullptr, qkv6, cD, cD, 0, 0, 0, 0);
        attn_k<<<dim3(cH, cB, 2), 256, 0, stream>>>(
            qkv6, kvc + (long)(2 * l) * ND, kvc + (long)(2 * l + 1) * ND, ob2, 0, 0, 0);
        gemm8_k<1, 1, false><<<gDD, 512, 0, stream>>>(
            ob2, nullptr, nullptr, nullptr, nullptr, nullptr, nullptr, 99,
            wDD + (long)(22 + l) * DD, nullptr, x_d, x_d, nullptr, cD, cD, 0, 0, 0, 0);
        // FFN
        gemm8_k<2, 2, true><<<gFFN1, 512, 0, stream>>>(
            nullptr, x_d, dec_ln3 + (long)(2 * l) * cD, dec_ln3 + (long)(2 * l + 1) * cD,
            nullptr, nullptr, nullptr, 99,
            wDF + (long)(2 + l) * DF, dec_b1 + (long)l * cF, nullptr, nullptr, hb_bf,
            cF, cD, 1, 0, 0, 0);
        gemm8_k<1, 1, false><<<gDD, 512, 0, stream>>>(
            hb_bf, nullptr, nullptr, nullptr, nullptr, nullptr, nullptr, 99,
            wFD + (long)(2 + l) * DF, dec_b2 + (long)l * cD, x_d, x_d, nullptr,
            cD, cF, 0, 0, 0, 0);
    }

    // ---- final LN + generator (fp32 W direct, fp16 logits) + log_softmax ----
    ln_k<<<cN, 256, 0, stream>>>(x_d, dec_lnf, dec_lnf + cD, xn_bf);
    gen32_k<<<dim3(cV / 128, cN / 128), 256, 0, stream>>>(
        xn_bf, gen_W, gen_b, lg16, cV, cD);
    lsm_k<<<cN, 256, 0, stream>>>(lg16, (float*)d_out);
}

// Round 11
// 308.677 us; speedup vs baseline: 1.4604x; 1.1113x over previous
//
#include <hip/hip_runtime.h>
#include <cstddef>

// Problem constants (from reference)
constexpr int cB = 4, cS = 128, cD = 512, cH = 8, cDK = 64, cF = 2048, cL = 2, cV = 32000;
constexpr int cN = cB * cS; // 512

typedef __attribute__((ext_vector_type(8)))  short short8;  // 8 x bf16 (MFMA frag)
typedef __attribute__((ext_vector_type(4)))  float f32x4;
typedef __attribute__((ext_vector_type(16))) float f32x16;  // 32x32 MFMA acc

__device__ __forceinline__ short f2bf(float x) {            // RNE fp32->bf16
    unsigned u = __builtin_bit_cast(unsigned, x);
    unsigned r = (u + 0x7fffu + ((u >> 16) & 1u)) >> 16;
    return (short)r;
}
__device__ __forceinline__ short f2h(float x) {             // fp32 -> fp16 bits
    return __builtin_bit_cast(short, (_Float16)x);
}
__device__ __forceinline__ float h2f(short s) {
    return (float)__builtin_bit_cast(_Float16, s);
}

// Raw barrier: waits LDS ops only (lgkmcnt). Global loads stay IN FLIGHT
// across the barrier (unlike __syncthreads, which drains vmcnt(0)).
__device__ __forceinline__ void bar_lgkm() {
    asm volatile("s_waitcnt lgkmcnt(0)" ::: "memory");
    __builtin_amdgcn_s_barrier();
    asm volatile("" ::: "memory");
}

// ---------------------------------------------------------------------------
// Embedding + positional encoding, both streams in one launch (z = 0/1)
// ---------------------------------------------------------------------------
__global__ __launch_bounds__(256) void embed_k(const float* __restrict__ e0,
                                               const int* __restrict__ t0,
                                               float* __restrict__ X0,
                                               const float* __restrict__ e1,
                                               const int* __restrict__ t1,
                                               float* __restrict__ X1)
{
    const float* emb = blockIdx.z ? e1 : e0;
    const int* tok   = blockIdx.z ? t1 : t0;
    float* X         = blockIdx.z ? X1 : X0;
    int n = blockIdx.x;
    int tid = threadIdx.x;
    int t = tok[n];
    int pos = n & (cS - 1);
    const float scale = 22.62741699796952f; // sqrt(512)
    for (int d = tid; d < cD; d += 256) {
        int i2 = d & ~1;
        float div = expf(-9.210340371976184f * (float)i2 / (float)cD);
        float arg = (float)pos * div;
        float p = (d & 1) ? cosf(arg) : sinf(arg);
        X[(long)n * cD + d] = emb[(long)t * cD + d] * scale + p;
    }
}

// ---------------------------------------------------------------------------
// LayerNorm -> bf16 (used once, before the generator GEMM)
// ---------------------------------------------------------------------------
__global__ __launch_bounds__(256) void ln_k(const float* __restrict__ X,
                                            const float* __restrict__ g,
                                            const float* __restrict__ bta,
                                            short* __restrict__ Yb)
{
    __shared__ float red[256];
    int row = blockIdx.x, tid = threadIdx.x;
    const float* x = X + (long)row * cD;
    float v0 = x[tid], v1 = x[tid + 256];

    red[tid] = v0 + v1;
    __syncthreads();
    for (int st = 128; st > 0; st >>= 1) { if (tid < st) red[tid] += red[tid + st]; __syncthreads(); }
    float mu = red[0] * (1.0f / (float)cD);
    __syncthreads();

    float d0 = v0 - mu, d1 = v1 - mu;
    red[tid] = d0 * d0 + d1 * d1;
    __syncthreads();
    for (int st = 128; st > 0; st >>= 1) { if (tid < st) red[tid] += red[tid + st]; __syncthreads(); }
    float var = red[0] * (1.0f / (float)cD);
    float rs = rsqrtf(var + 1e-5f);

    Yb[(long)row * cD + tid]       = f2bf(g[tid]       * d0 * rs + bta[tid]);
    Yb[(long)row * cD + tid + 256] = f2bf(g[tid + 256] * d1 * rs + bta[tid + 256]);
}

// ---------------------------------------------------------------------------
// Batched transpose-convert: z slices fp32 [K][N] -> bf16 [N][K] contiguous.
// ---------------------------------------------------------------------------
struct TCP { const float* s[24]; };

__global__ __launch_bounds__(256) void tconv_k(TCP ptrs, short* __restrict__ dst,
                                               int K, int N)
{
    __shared__ float t[64][65];
    const float* s = ptrs.s[blockIdx.z];
    short* d = dst + (long)blockIdx.z * K * N;
    int k0 = blockIdx.y * 64, n0 = blockIdx.x * 64;
    int tid = threadIdx.x;
    const f32x4* s4 = (const f32x4*)s;
#pragma unroll
    for (int i = 0; i < 4; i++) {
        int lin = tid + i * 256;
        int r = lin >> 4, c4 = lin & 15;
        f32x4 v = s4[(long)(k0 + r) * (N >> 2) + (n0 >> 2) + c4];
        t[r][c4 * 4 + 0] = v[0]; t[r][c4 * 4 + 1] = v[1];
        t[r][c4 * 4 + 2] = v[2]; t[r][c4 * 4 + 3] = v[3];
    }
    __syncthreads();
#pragma unroll
    for (int i = 0; i < 2; i++) {
        int lin = tid + i * 256;
        int r = lin >> 3, c8 = lin & 7;
        short8 o;
#pragma unroll
        for (int j = 0; j < 8; j++) o[j] = f2bf(t[c8 * 8 + j][r]);
        *(short8*)&d[(long)(n0 + r) * K + k0 + c8 * 8] = o;
    }
}

// ---------------------------------------------------------------------------
// 8-wave split-K bf16 MFMA GEMM.  C = act(LN?(A) @ B + bias) + res
// K = KSTEPS*128 (template). For KSTEPS <= 4: ALL tile loads issued at t=0
// (full-depth static register queue, one memory latency total). KSTEPS > 4:
// rolled depth-2 prefetch. Raw lgkm barriers throughout (prefetch survives).
// zsplit: blocks with z >= zsplit read Af2/lng2/lnb2 (stream merge).
// aStride: per-z offset on the bf16 A operand (merged O-projection).
// ---------------------------------------------------------------------------
template <int MR, int NR, bool LNF, int KSTEPS>
__global__ __launch_bounds__(512) void gemm8_k(
    const short* __restrict__ Abf, const float* __restrict__ Af,
    const float* __restrict__ lng, const float* __restrict__ lnb,
    const float* __restrict__ Af2, const float* __restrict__ lng2,
    const float* __restrict__ lnb2, int zsplit,
    const short* __restrict__ Bt,
    const float* __restrict__ bias, const float* __restrict__ res,
    float* __restrict__ C, short* __restrict__ Cb,
    int N, int relu, long aStride, long btStride, long cStride)
{
    constexpr int K = KSTEPS * 128;
    constexpr int BM = MR * 32, BN = NR * 32, PITCH = 136; // 128 + 8
    constexpr int ACH = (BM * 128) / (8 * 512);
    constexpr int BCH = (BN * 128) / (8 * 512);
    static_assert(ACH >= 1 && BCH >= 1, "tile too small");
    static_assert(!LNF || KSTEPS <= 4, "LNF only on short-K path");
    __shared__ short As[2][BM * PITCH];
    __shared__ short Bs[2][BN * PITCH];
    __shared__ float red[4][64][MR * NR * 4];
    __shared__ float mu_s[BM], rs_s[BM];
    __shared__ float gb_s[2][LNF ? 512 : 8];

    const int z = blockIdx.z;
    const float* Afz = (LNF && z >= zsplit) ? Af2 : Af;
    const float* gz  = (LNF && z >= zsplit) ? lng2 : lng;
    const float* bz  = (LNF && z >= zsplit) ? lnb2 : lnb;
    const short* Am = Abf ? (Abf + (long)z * aStride) : nullptr;
    const short* Bm = Bt + (long)z * btStride;
    int tid = threadIdx.x;
    int lane = tid & 63, wid = tid >> 6;
    int grp = wid >> 2, quad = wid & 3;
    int wr = quad >> 1, wc = quad & 1;
    int m0 = blockIdx.y * BM, n0 = blockIdx.x * BN;
    int lrow = lane & 15, koff = (lane >> 4) * 8;
    const int Kh = K >> 1;

    f32x4 acc[MR][NR];
#pragma unroll
    for (int m = 0; m < MR; m++)
#pragma unroll
        for (int n = 0; n < NR; n++) acc[m][n] = f32x4{0.f, 0.f, 0.f, 0.f};

    constexpr int FAN = LNF ? ACH * 2 : 1;

    auto stageA = [&](int step, short8 (&qa)[ACH], f32x4 (&fa)[FAN]) {
#pragma unroll
        for (int i = 0; i < ACH; i++) {
            int lin = tid + i * 512, r = lin >> 4, c8 = lin & 15;
            int kg = (c8 < 8) ? (step * 64 + c8 * 8) : (Kh + step * 64 + (c8 - 8) * 8);
            if constexpr (LNF) {
                const f32x4* p = (const f32x4*)(Afz + (long)(m0 + r) * K + kg);
                fa[2 * i] = p[0]; fa[2 * i + 1] = p[1];
            } else {
                qa[i] = *(const short8*)&Am[(long)(m0 + r) * K + kg];
            }
        }
    };
    auto stageB = [&](int step, short8 (&qb)[BCH]) {
#pragma unroll
        for (int i = 0; i < BCH; i++) {
            int lin = tid + i * 512, r = lin >> 4, c8 = lin & 15;
            int kg = (c8 < 8) ? (step * 64 + c8 * 8) : (Kh + step * 64 + (c8 - 8) * 8);
            qb[i] = *(const short8*)&Bm[(long)(n0 + r) * K + kg];
        }
    };
    auto writeT = [&](int buf, int step, short8 (&qa)[ACH], f32x4 (&fa)[FAN],
                      short8 (&qb)[BCH]) {
#pragma unroll
        for (int i = 0; i < ACH; i++) {
            int lin = tid + i * 512, r = lin >> 4, c8 = lin & 15;
            if constexpr (LNF) {
                int kg = (c8 < 8) ? (step * 64 + c8 * 8) : (Kh + step * 64 + (c8 - 8) * 8);
                float mu = mu_s[r], rs = rs_s[r];
                short8 o;
#pragma unroll
                for (int j = 0; j < 4; j++)
                    o[j] = f2bf((fa[2 * i][j] - mu) * rs * gb_s[0][kg + j] + gb_s[1][kg + j]);
#pragma unroll
                for (int j = 0; j < 4; j++)
                    o[4 + j] = f2bf((fa[2 * i + 1][j] - mu) * rs * gb_s[0][kg + 4 + j] + gb_s[1][kg + 4 + j]);
                *(short8*)&As[buf][r * PITCH + c8 * 8] = o;
            } else {
                *(short8*)&As[buf][r * PITCH + c8 * 8] = qa[i];
            }
        }
#pragma unroll
        for (int i = 0; i < BCH; i++) {
            int lin = tid + i * 512, r = lin >> 4, c8 = lin & 15;
            *(short8*)&Bs[buf][r * PITCH + c8 * 8] = qb[i];
        }
    };
    auto mfmaStep = [&](int buf) {
#pragma unroll
        for (int kk2 = 0; kk2 < 2; kk2++) {
            int kk = grp * 64 + kk2 * 32;
            short8 a[MR], b[NR];
#pragma unroll
            for (int m = 0; m < MR; m++)
                a[m] = *(const short8*)&As[buf][(wr * MR * 16 + m * 16 + lrow) * PITCH + kk + koff];
#pragma unroll
            for (int n = 0; n < NR; n++)
                b[n] = *(const short8*)&Bs[buf][(wc * NR * 16 + n * 16 + lrow) * PITCH + kk + koff];
#pragma unroll
            for (int m = 0; m < MR; m++)
#pragma unroll
                for (int n = 0; n < NR; n++)
                    acc[m][n] = __builtin_amdgcn_mfma_f32_16x16x32_bf16(a[m], b[n], acc[m][n], 0, 0, 0);
        }
    };
    auto lnProlog = [&]() {
        if constexpr (LNF) {
            constexpr int TPR = 512 / BM;
            int r = tid / TPR, sub = tid % TPR;
            const f32x4* row4 = (const f32x4*)(Afz + (long)(m0 + r) * K);
            float s = 0.f, s2 = 0.f;
            for (int i = sub; i < (K >> 2); i += TPR) {
                f32x4 v = row4[i];
                s  += v[0] + v[1] + v[2] + v[3];
                s2 += v[0] * v[0] + v[1] * v[1] + v[2] * v[2] + v[3] * v[3];
            }
#pragma unroll
            for (int o = TPR >> 1; o > 0; o >>= 1) {
                s += __shfl_xor(s, o); s2 += __shfl_xor(s2, o);
            }
            if (sub == 0) {
                float mu = s / (float)K;
                float var = s2 / (float)K - mu * mu;
                mu_s[r] = mu; rs_s[r] = rsqrtf(var + 1e-5f);
            }
            if (tid < 512) { gb_s[0][tid] = gz[tid]; gb_s[1][tid] = bz[tid]; }
            bar_lgkm();
        }
    };

    if constexpr (KSTEPS <= 4) {
        // full-depth: all tile loads in flight before anything is consumed
        short8 qa[KSTEPS][ACH], qb[KSTEPS][BCH];
        f32x4 fa[LNF ? KSTEPS : 1][FAN];
#pragma unroll
        for (int s = 0; s < KSTEPS; s++) {
            stageA(s, qa[s], fa[LNF ? s : 0]);
            stageB(s, qb[s]);
        }
        lnProlog();
#pragma unroll
        for (int s = 0; s < KSTEPS; s++) {
            writeT(s & 1, s, qa[s], fa[LNF ? s : 0], qb[s]);
            bar_lgkm();
            mfmaStep(s & 1);
            if (s + 1 < KSTEPS) bar_lgkm();   // mfma(s) frag reads complete before buf reuse
        }
    } else {
        // rolled depth-2 (FFN2: KSTEPS=16, non-LNF)
        short8 qa0[ACH], qa1[ACH], qb0[BCH], qb1[BCH];
        f32x4 fdum[FAN];
        stageA(0, qa0, fdum); stageB(0, qb0);
        stageA(1, qa1, fdum); stageB(1, qb1);
        int st = 0;
        for (;;) {
            writeT(0, st, qa0, fdum, qb0);
            if (st + 2 < KSTEPS) { stageA(st + 2, qa0, fdum); stageB(st + 2, qb0); }
            bar_lgkm();
            mfmaStep(0);
            st++; if (st >= KSTEPS) break;

            writeT(1, st, qa1, fdum, qb1);
            if (st + 2 < KSTEPS) { stageA(st + 2, qa1, fdum); stageB(st + 2, qb1); }
            bar_lgkm();
            mfmaStep(1);
            st++; if (st >= KSTEPS) break;
        }
    }

    // cross-group reduction: grp1 -> LDS, grp0 adds + epilogue
    __syncthreads();
    if (grp == 1) {
#pragma unroll
        for (int m = 0; m < MR; m++)
#pragma unroll
            for (int n = 0; n < NR; n++)
#pragma unroll
                for (int j = 0; j < 4; j++)
                    red[quad][lane][(m * NR + n) * 4 + j] = acc[m][n][j];
    }
    __syncthreads();
    if (grp == 0) {
#pragma unroll
        for (int m = 0; m < MR; m++) {
            int rbase = m0 + wr * MR * 16 + m * 16 + (lane >> 4) * 4;
#pragma unroll
            for (int n = 0; n < NR; n++) {
                int col = n0 + wc * NR * 16 + n * 16 + (lane & 15);
                float bv = bias ? bias[col] : 0.f;
#pragma unroll
                for (int j = 0; j < 4; j++) {
                    long row = rbase + j;
                    long off = row * N + col + (long)z * cStride;
                    float v = acc[m][n][j] + red[quad][lane][(m * NR + n) * 4 + j] + bv;
                    if (res)  v += res[off];
                    if (relu) v = fmaxf(v, 0.f);
                    if (C)  C[off] = v;
                    if (Cb) Cb[off] = f2bf(v);
                }
            }
        }
    }
}

// ---------------------------------------------------------------------------
// MFMA attention, multi-stream: grid z = (stream<<1) | dstHalf.
// Q/K/V/O base + per-stream strides; causal = (causMask >> stream) & 1.
//   s = exp(clip(q.k/8, +-10)); o = sum(s*v)/sum(s); causal masks src>dst.
// ---------------------------------------------------------------------------
__global__ __launch_bounds__(256) void attn_k(const short* __restrict__ Qb,
                                              const short* __restrict__ Kb,
                                              const short* __restrict__ Vb,
                                              short* __restrict__ Ob,
                                              int causMask, long sQKV, long sO)
{
    __shared__ short q_s[64 * 72];     // [dst][dk]  pitch 72
    __shared__ short k_s[128 * 72];    // [src][dk]  pitch 72
    __shared__ short vt_s[64 * 128];   // [dk][src]  granule-swizzled, pitch 128
    __shared__ short p_s[64 * 136];    // [dst][src] pitch 136
    __shared__ float z_s[64];

    int tid = threadIdx.x, lane = tid & 63, wid = tid >> 6;
    int lr = lane & 15, lg = lane >> 4;
    int h = blockIdx.x, b = blockIdx.y;
    int stream = blockIdx.z >> 1, dstBase = (blockIdx.z & 1) * 64;
    int causal = (causMask >> stream) & 1;
    const short* Q = Qb + (long)stream * sQKV;
    const short* Km = Kb + (long)stream * sQKV;
    const short* Vm = Vb + (long)stream * sQKV;
    short* O = Ob + (long)stream * sO;
    const int RS = cH * cDK; // 512
    long qbase = ((long)b * cS + dstBase) * RS + h * cDK;
    long kbase = ((long)b * cS) * RS + h * cDK;

#pragma unroll
    for (int i = 0; i < 2; i++) {
        int lin = tid + i * 256, t = lin >> 3, c8 = lin & 7;
        *(short8*)&q_s[t * 72 + c8 * 8] = *(const short8*)&Q[qbase + (long)t * RS + c8 * 8];
    }
#pragma unroll
    for (int i = 0; i < 4; i++) {
        int lin = tid + i * 256, t = lin >> 3, c8 = lin & 7;
        *(short8*)&k_s[t * 72 + c8 * 8] = *(const short8*)&Km[kbase + (long)t * RS + c8 * 8];
    }
#pragma unroll
    for (int i = 0; i < 4; i++) {
        int lin = tid + i * 256, src = lin >> 3, c8 = lin & 7;
        short8 v = *(const short8*)&Vm[kbase + (long)src * RS + c8 * 8];
#pragma unroll
        for (int j = 0; j < 8; j++) {
            int dk = c8 * 8 + j;
            int g = (src >> 3) ^ (dk >> 3);
            vt_s[dk * 128 + g * 8 + (src & 7)] = v[j];
        }
    }
    bar_lgkm();

    // ---- S = q @ k^T : wave computes 16 dst rows x 128 src ----
    f32x4 sacc[8];
#pragma unroll
    for (int n = 0; n < 8; n++) sacc[n] = f32x4{0.f, 0.f, 0.f, 0.f};
#pragma unroll
    for (int kk = 0; kk < 64; kk += 32) {
        short8 a = *(const short8*)&q_s[(wid * 16 + lr) * 72 + kk + lg * 8];
#pragma unroll
        for (int n = 0; n < 8; n++) {
            short8 bf = *(const short8*)&k_s[(n * 16 + lr) * 72 + kk + lg * 8];
            sacc[n] = __builtin_amdgcn_mfma_f32_16x16x32_bf16(a, bf, sacc[n], 0, 0, 0);
        }
    }
    float z[4] = {0.f, 0.f, 0.f, 0.f};
#pragma unroll
    for (int n = 0; n < 8; n++) {
        int src = n * 16 + lr;
#pragma unroll
        for (int j = 0; j < 4; j++) {
            int dst = dstBase + wid * 16 + lg * 4 + j;
            float s = sacc[n][j] * 0.125f;
            s = __expf(fminf(fmaxf(s, -10.f), 10.f));
            if (causal && src > dst) s = 0.f;
            sacc[n][j] = s;
            z[j] += s;
        }
    }
#pragma unroll
    for (int j = 0; j < 4; j++) {
        z[j] += __shfl_xor(z[j], 1); z[j] += __shfl_xor(z[j], 2);
        z[j] += __shfl_xor(z[j], 4); z[j] += __shfl_xor(z[j], 8);
    }
#pragma unroll
    for (int n = 0; n < 8; n++) {
        int src = n * 16 + lr;
#pragma unroll
        for (int j = 0; j < 4; j++)
            p_s[(wid * 16 + lg * 4 + j) * 136 + src] = f2bf(sacc[n][j]);
    }
    if (lr == 0) {
#pragma unroll
        for (int j = 0; j < 4; j++) z_s[wid * 16 + lg * 4 + j] = z[j];
    }
    bar_lgkm();

    // ---- O^T[dk][dst] = vt @ p^T ----
    f32x4 oacc[4];
#pragma unroll
    for (int n = 0; n < 4; n++) oacc[n] = f32x4{0.f, 0.f, 0.f, 0.f};
#pragma unroll
    for (int kk = 0; kk < 128; kk += 32) {
        int dkr = wid * 16 + lr;
        int g = ((kk >> 3) + lg) ^ (dkr >> 3);
        short8 a = *(const short8*)&vt_s[dkr * 128 + g * 8];
#pragma unroll
        for (int n = 0; n < 4; n++) {
            short8 bf = *(const short8*)&p_s[(n * 16 + lr) * 136 + kk + lg * 8];
            oacc[n] = __builtin_amdgcn_mfma_f32_16x16x32_bf16(a, bf, oacc[n], 0, 0, 0);
        }
    }
#pragma unroll
    for (int n = 0; n < 4; n++) {
        int dl = n * 16 + lr;
        float zz = z_s[dl];
#pragma unroll
        for (int j = 0; j < 4; j++) {
            int dk = wid * 16 + lg * 4 + j;
            O[qbase + (long)dl * RS + dk] = f2bf(oacc[n][j] / zz);
        }
    }
}

// ---------------------------------------------------------------------------
// Generator GEMM, 32x32x16 MFMA: R6 core (BK=64, PITCH=72, dbuf, 0 bank
// conflicts) + raw lgkm barriers + depth-2 reg prefetch. bf16 genT input,
// fp16 logits out, XCD swizzle.
// ---------------------------------------------------------------------------
__global__ __launch_bounds__(256) void gen32_k(
    const short* __restrict__ A, const short* __restrict__ Bt,
    const float* __restrict__ bias, short* __restrict__ Ch, int N, int K)
{
    constexpr int PITCH = 72;
    constexpr int ACH = 4, BCH = 4;    // 128*64/2048
    __shared__ short As[2][128 * PITCH];
    __shared__ short Bs[2][128 * PITCH];

    int bx = blockIdx.x, by = blockIdx.y;
    {   // XCD swizzle (grid 250x4 = 1000, 1000 % 8 == 0)
        int nb = gridDim.x * gridDim.y;
        int bid = by * gridDim.x + bx;
        int w = (bid & 7) * (nb >> 3) + (bid >> 3);
        by = w % gridDim.y; bx = w / gridDim.y;
    }
    int tid = threadIdx.x;
    int lane = tid & 63, wid = tid >> 6;
    int wr = wid >> 1, wc = wid & 1;
    int m0 = by * 128, n0 = bx * 128;
    int l31 = lane & 31, l5 = lane >> 5;

    f32x16 acc[2][2];
#pragma unroll
    for (int m = 0; m < 2; m++)
#pragma unroll
        for (int n = 0; n < 2; n++)
#pragma unroll
            for (int r = 0; r < 16; r++) acc[m][n][r] = 0.f;

    short8 qa0[ACH], qa1[ACH], qb0[BCH], qb1[BCH];
    auto stage = [&](int k0, short8 (&qa)[ACH], short8 (&qb)[BCH]) {
#pragma unroll
        for (int i = 0; i < ACH; i++) {
            int lin = tid + i * 256, r = lin >> 3, c8 = lin & 7;
            qa[i] = *(const short8*)&A[(long)(m0 + r) * K + k0 + c8 * 8];
        }
#pragma unroll
        for (int i = 0; i < BCH; i++) {
            int lin = tid + i * 256, r = lin >> 3, c8 = lin & 7;
            qb[i] = *(const short8*)&Bt[(long)(n0 + r) * K + k0 + c8 * 8];
        }
    };
    auto writeT = [&](int buf, short8 (&qa)[ACH], short8 (&qb)[BCH]) {
#pragma unroll
        for (int i = 0; i < ACH; i++) {
            int lin = tid + i * 256, r = lin >> 3, c8 = lin & 7;
            *(short8*)&As[buf][r * PITCH + c8 * 8] = qa[i];
        }
#pragma unroll
        for (int i = 0; i < BCH; i++) {
            int lin = tid + i * 256, r = lin >> 3, c8 = lin & 7;
            *(short8*)&Bs[buf][r * PITCH + c8 * 8] = qb[i];
        }
    };
    auto mfmaStep = [&](int buf) {
#pragma unroll
        for (int kk = 0; kk < 64; kk += 16) {
            short8 a[2], b[2];
#pragma unroll
            for (int m = 0; m < 2; m++)
                a[m] = *(const short8*)&As[buf][(wr * 64 + m * 32 + l31) * PITCH + kk + l5 * 8];
#pragma unroll
            for (int n = 0; n < 2; n++)
                b[n] = *(const short8*)&Bs[buf][(wc * 64 + n * 32 + l31) * PITCH + kk + l5 * 8];
#pragma unroll
            for (int m = 0; m < 2; m++)
#pragma unroll
                for (int n = 0; n < 2; n++)
                    acc[m][n] = __builtin_amdgcn_mfma_f32_32x32x16_bf16(a[m], b[n], acc[m][n], 0, 0, 0);
        }
    };

    const int steps = K >> 6;   // 8
    stage(0, qa0, qb0);
    stage(64, qa1, qb1);
    int st = 0;
    for (;;) {
        writeT(0, qa0, qb0);
        if (st + 2 < steps) stage((st + 2) * 64, qa0, qb0);
        bar_lgkm();
        mfmaStep(0);
        st++; if (st >= steps) break;

        writeT(1, qa1, qb1);
        if (st + 2 < steps) stage((st + 2) * 64, qa1, qb1);
        bar_lgkm();
        mfmaStep(1);
        st++; if (st >= steps) break;
    }

    // epilogue: 32x32 C/D layout col=lane&31, row=(r&3)+8*(r>>2)+4*(lane>>5)
#pragma unroll
    for (int m = 0; m < 2; m++) {
#pragma unroll
        for (int n = 0; n < 2; n++) {
            int col = n0 + wc * 64 + n * 32 + l31;
            float bv = bias[col];
#pragma unroll
            for (int r = 0; r < 16; r++) {
                int row = m0 + wr * 64 + m * 32 + (r & 3) + 8 * (r >> 2) + 4 * l5;
                Ch[(long)row * N + col] = f2h(acc[m][n][r] + bv);
            }
        }
    }
}

// ---------------------------------------------------------------------------
// Row log_softmax over V=32000: fp16 logits in, fp32 out.
// ---------------------------------------------------------------------------
__global__ __launch_bounds__(256) void lsm_k(const short* __restrict__ L16,
                                             float* __restrict__ Out)
{
    __shared__ float rm[256], rs[256];
    int row = blockIdx.x, tid = threadIdx.x;
    const short8* x8 = (const short8*)(L16 + (long)row * cV);
    float* o = Out + (long)row * cV;
    constexpr int NV = cV / 8;   // 4000

    float m = -1e30f, s = 0.f;
    for (int i = tid; i < NV; i += 256) {
        short8 v = x8[i];
        float f[8];
#pragma unroll
        for (int j = 0; j < 8; j++) f[j] = h2f(v[j]);
        float cm = f[0];
#pragma unroll
        for (int j = 1; j < 8; j++) cm = fmaxf(cm, f[j]);
        float nm = fmaxf(m, cm);
        float a = 0.f;
#pragma unroll
        for (int j = 0; j < 8; j++) a += __expf(f[j] - nm);
        s = s * __expf(m - nm) + a;
        m = nm;
    }
    rm[tid] = m; rs[tid] = s;
    __syncthreads();
    for (int st = 128; st > 0; st >>= 1) {
        if (tid < st) {
            float m2 = rm[tid + st], s2 = rs[tid + st];
            float nm = fmaxf(rm[tid], m2);
            rs[tid] = rs[tid] * __expf(rm[tid] - nm) + s2 * __expf(m2 - nm);
            rm[tid] = nm;
        }
        __syncthreads();
    }
    float lse = rm[0] + __logf(rs[0]);

    for (int i = tid; i < NV; i += 256) {
        short8 v = x8[i];
        f32x4 o0, o1;
#pragma unroll
        for (int j = 0; j < 4; j++) o0[j] = h2f(v[j]) - lse;
#pragma unroll
        for (int j = 0; j < 4; j++) o1[j] = h2f(v[4 + j]) - lse;
        *(f32x4*)&o[i * 8]     = o0;
        *(f32x4*)&o[i * 8 + 4] = o1;
    }
}

// ---------------------------------------------------------------------------
extern "C" void kernel_launch(void* const* d_in, const int* in_sizes, int n_in,
                              void* d_out, int out_size, void* d_ws, size_t ws_size,
                              hipStream_t stream)
{
    const float* src_emb  = (const float*)d_in[0];
    const float* tgt_emb  = (const float*)d_in[1];
    const float* enc_Wqkv = (const float*)d_in[2];
    const float* enc_Wo   = (const float*)d_in[3];
    const float* enc_ln1  = (const float*)d_in[4];
    const float* enc_W1   = (const float*)d_in[5];
    const float* enc_b1   = (const float*)d_in[6];
    const float* enc_W2   = (const float*)d_in[7];
    const float* enc_b2   = (const float*)d_in[8];
    const float* enc_ln2  = (const float*)d_in[9];
    const float* enc_lnf  = (const float*)d_in[10];
    const float* dec_Wqkv = (const float*)d_in[11];
    const float* dec_Wo   = (const float*)d_in[12];
    const float* dec_ln1  = (const float*)d_in[13];
    const float* dec_cWq  = (const float*)d_in[14];
    const float* dec_cWkv = (const float*)d_in[15];
    const float* dec_cWo  = (const float*)d_in[16];
    const float* dec_ln2  = (const float*)d_in[17];
    const float* dec_W1   = (const float*)d_in[18];
    const float* dec_b1   = (const float*)d_in[19];
    const float* dec_W2   = (const float*)d_in[20];
    const float* dec_b2   = (const float*)d_in[21];
    const float* dec_ln3  = (const float*)d_in[22];
    const float* dec_lnf  = (const float*)d_in[23];
    const float* gen_W    = (const float*)d_in[24];
    const float* gen_b    = (const float*)d_in[25];
    const int* src_tok    = (const int*)d_in[26];
    const int* tgt_tok    = (const int*)d_in[27];
    // edge lists (28..33): fixed structure (full / causal) -> unused

    const long ND = (long)cN * cD;          // 262144
    const long DD = (long)cD * cD;          // 262144
    const long DF = (long)cD * cF;          // 1048576

    // fp32 region (x_e and x_d adjacent: merged O-proj uses stride ND)
    float* x_e = (float*)d_ws;
    float* x_d = x_e + ND;

    // bf16 region
    short* qkv6  = (short*)(x_d + ND);      // [6][N,D]
    short* ob2   = qkv6 + 6 * ND;           // [2][N,D] attn out (enc, dec)
    short* hb_bf = ob2 + 2 * ND;            // [N,F]
    short* kvc   = hb_bf + (long)cN * cF;   // [4][N,D] cross K/V (l0k,l0v,l1k,l1v)
    short* xn_bf = kvc + 4 * ND;            // [N,D]
    short* wDD  = xn_bf + ND;               // 24 x [D][D]
    short* wDF  = wDD + 24 * DD;            // 4  x [F][D]  (W1 slices)
    short* wFD  = wDF + 4 * DF;             // 4  x [D][F]  (W2 slices)
    short* genT = wFD + 4 * DF;             // [V][D]
    short* lg16 = genT + (long)cD * cV;     // [N][V] fp16 logits

    // wDD slice order:
    //  0-2 enc_Wqkv l0 | 3-5 dec_Wqkv l0 | 6 enc_Wo l0 | 7 dec_Wo l0
    //  8-10 enc_Wqkv l1 | 11 dec_cWq l0 | 12-14 dec_Wqkv l1 | 15 enc_Wo l1
    //  16 dec_Wo l1 | 17 dec_cWq l1 | 18-21 dec_cWkv | 22-23 dec_cWo
    {
        TCP p{};
        int i = 0;
        for (int j = 0; j < 3; j++) p.s[i++] = enc_Wqkv + (long)j * DD;
        for (int j = 0; j < 3; j++) p.s[i++] = dec_Wqkv + (long)j * DD;
        p.s[i++] = enc_Wo; p.s[i++] = dec_Wo;
        for (int j = 3; j < 6; j++) p.s[i++] = enc_Wqkv + (long)j * DD;
        p.s[i++] = dec_cWq;
        for (int j = 3; j < 6; j++) p.s[i++] = dec_Wqkv + (long)j * DD;
        p.s[i++] = enc_Wo + DD;
        p.s[i++] = dec_Wo + DD;
        p.s[i++] = dec_cWq + DD;
        for (int j = 0; j < 4; j++) p.s[i++] = dec_cWkv + (long)j * DD;
        for (int j = 0; j < 2; j++) p.s[i++] = dec_cWo  + (long)j * DD;
        tconv_k<<<dim3(cD / 64, cD / 64, 24), 256, 0, stream>>>(p, wDD, cD, cD);
    }
    {
        TCP p{};
        p.s[0] = enc_W1; p.s[1] = enc_W1 + DF; p.s[2] = dec_W1; p.s[3] = dec_W1 + DF;
        tconv_k<<<dim3(cF / 64, cD / 64, 4), 256, 0, stream>>>(p, wDF, cD, cF);
    }
    {
        TCP p{};
        p.s[0] = enc_W2; p.s[1] = enc_W2 + DF; p.s[2] = dec_W2; p.s[3] = dec_W2 + DF;
        tconv_k<<<dim3(cD / 64, cF / 64, 4), 256, 0, stream>>>(p, wFD, cF, cD);
    }
    {
        TCP p{};
        p.s[0] = gen_W;
        tconv_k<<<dim3(cV / 64, cD / 64, 1), 256, 0, stream>>>(p, genT, cD, cV);
    }

    embed_k<<<dim3(cN, 1, 2), 256, 0, stream>>>(src_emb, src_tok, x_e,
                                                tgt_emb, tgt_tok, x_d);

    dim3 gDD(cD / 32, cN / 32);            // 256 blocks
    dim3 gFFN1(cF / 64, cN / 64);          // 256 blocks, <2,2>

    // ====== merged: enc l0 self QKV + dec l0 self QKV (z=6, zsplit=3) ======
    gemm8_k<1, 1, true, 4><<<dim3(cD / 32, cN / 32, 6), 512, 0, stream>>>(
        nullptr, x_e, enc_ln1, enc_ln1 + cD,
        x_d, dec_ln1, dec_ln1 + cD, 3,
        wDD, nullptr, nullptr, nullptr, qkv6, cD, 0, 0, DD, ND);
    attn_k<<<dim3(cH, cB, 4), 256, 0, stream>>>(
        qkv6, qkv6 + ND, qkv6 + 2 * ND, ob2, 0b10, 3 * ND, ND);
    gemm8_k<1, 1, false, 4><<<dim3(cD / 32, cN / 32, 2), 512, 0, stream>>>(
        ob2, nullptr, nullptr, nullptr, nullptr, nullptr, nullptr, 99,
        wDD + 6 * DD, nullptr, x_e, x_e, nullptr, cD, 0, ND, DD, ND);

    // ====== encoder layer0 FFN ======
    gemm8_k<2, 2, true, 4><<<gFFN1, 512, 0, stream>>>(
        nullptr, x_e, enc_ln2, enc_ln2 + cD, nullptr, nullptr, nullptr, 99,
        wDF, enc_b1, nullptr, nullptr, hb_bf, cF, 1, 0, 0, 0);
    gemm8_k<1, 1, false, 16><<<gDD, 512, 0, stream>>>(
        hb_bf, nullptr, nullptr, nullptr, nullptr, nullptr, nullptr, 99,
        wFD, enc_b2, x_e, x_e, nullptr, cD, 0, 0, 0, 0);

    // ====== merged: enc l1 QKV (z=0..2) + dec l0 cross Q (z=3) ======
    gemm8_k<1, 1, true, 4><<<dim3(cD / 32, cN / 32, 4), 512, 0, stream>>>(
        nullptr, x_e, enc_ln1 + 2 * cD, enc_ln1 + 3 * cD,
        x_d, dec_ln2, dec_ln2 + cD, 3,
        wDD + 8 * DD, nullptr, nullptr, nullptr, qkv6, cD, 0, 0, DD, ND);
    attn_k<<<dim3(cH, cB, 2), 256, 0, stream>>>(
        qkv6, qkv6 + ND, qkv6 + 2 * ND, ob2, 0, 0, 0);
    gemm8_k<1, 1, false, 4><<<gDD, 512, 0, stream>>>(
        ob2, nullptr, nullptr, nullptr, nullptr, nullptr, nullptr, 99,
        wDD + 15 * DD, nullptr, x_e, x_e, nullptr, cD, 0, 0, 0, 0);
    gemm8_k<2, 2, true, 4><<<gFFN1, 512, 0, stream>>>(
        nullptr, x_e, enc_ln2 + 2 * cD, enc_ln2 + 3 * cD,
        nullptr, nullptr, nullptr, 99,
        wDF + DF, enc_b1 + cF, nullptr, nullptr, hb_bf, cF, 1, 0, 0, 0);
    gemm8_k<1, 1, false, 16><<<gDD, 512, 0, stream>>>(
        hb_bf, nullptr, nullptr, nullptr, nullptr, nullptr, nullptr, 99,
        wFD + DF, enc_b2 + cD, x_e, x_e, nullptr, cD, 0, 0, 0, 0);

    // ====== cross K/V for both decoder layers (enc_lnf fused), z=4 ======
    gemm8_k<1, 1, true, 4><<<dim3(cD / 32, cN / 32, 4), 512, 0, stream>>>(
        nullptr, x_e, enc_lnf, enc_lnf + cD, nullptr, nullptr, nullptr, 99,
        wDD + 18 * DD, nullptr, nullptr, nullptr, kvc, cD, 0, 0, DD, ND);

    // ====== decoder layer0: cross-attn (Q precomputed in qkv6[3]) + FFN ======
    attn_k<<<dim3(cH, cB, 2), 256, 0, stream>>>(
        qkv6 + 3 * ND, kvc, kvc + ND, ob2, 0, 0, 0);
    gemm8_k<1, 1, false, 4><<<gDD, 512, 0, stream>>>(
        ob2, nullptr, nullptr, nullptr, nullptr, nullptr, nullptr, 99,
        wDD + 22 * DD, nullptr, x_d, x_d, nullptr, cD, 0, 0, 0, 0);
    gemm8_k<2, 2, true, 4><<<gFFN1, 512, 0, stream>>>(
        nullptr, x_d, dec_ln3, dec_ln3 + cD, nullptr, nullptr, nullptr, 99,
        wDF + 2 * DF, dec_b1, nullptr, nullptr, hb_bf, cF, 1, 0, 0, 0);
    gemm8_k<1, 1, false, 16><<<gDD, 512, 0, stream>>>(
        hb_bf, nullptr, nullptr, nullptr, nullptr, nullptr, nullptr, 99,
        wFD + 2 * DF, dec_b2, x_d, x_d, nullptr, cD, 0, 0, 0, 0);

    // ====== decoder layer1 ======
    gemm8_k<1, 1, true, 4><<<dim3(cD / 32, cN / 32, 3), 512, 0, stream>>>(
        nullptr, x_d, dec_ln1 + 2 * cD, dec_ln1 + 3 * cD,
        nullptr, nullptr, nullptr, 99,
        wDD + 12 * DD, nullptr, nullptr, nullptr, qkv6, cD, 0, 0, DD, ND);
    attn_k<<<dim3(cH, cB, 2), 256, 0, stream>>>(
        qkv6, qkv6 + ND, qkv6 + 2 * ND, ob2, 1, 0, 0);
    gemm8_k<1, 1, false, 4><<<gDD, 512, 0, stream>>>(
        ob2, nullptr, nullptr, nullptr, nullptr, nullptr, nullptr, 99,
        wDD + 16 * DD, nullptr, x_d, x_d, nullptr, cD, 0, 0, 0, 0);
    gemm8_k<1, 1, true, 4><<<gDD, 512, 0, stream>>>(
        nullptr, x_d, dec_ln2 + 2 * cD, dec_ln2 + 3 * cD,
        nullptr, nullptr, nullptr, 99,
        wDD + 17 * DD, nullptr, nullptr, nullptr, qkv6, cD, 0, 0, 0, 0);
    attn_k<<<dim3(cH, cB, 2), 256, 0, stream>>>(
        qkv6, kvc + 2 * ND, kvc + 3 * ND, ob2, 0, 0, 0);
    gemm8_k<1, 1, false, 4><<<gDD, 512, 0, stream>>>(
        ob2, nullptr, nullptr, nullptr, nullptr, nullptr, nullptr, 99,
        wDD + 23 * DD, nullptr, x_d, x_d, nullptr, cD, 0, 0, 0, 0);
    gemm8_k<2, 2, true, 4><<<gFFN1, 512, 0, stream>>>(
        nullptr, x_d, dec_ln3 + 2 * cD, dec_ln3 + 3 * cD,
        nullptr, nullptr, nullptr, 99,
        wDF + 3 * DF, dec_b1 + cF, nullptr, nullptr, hb_bf, cF, 1, 0, 0, 0);
    gemm8_k<1, 1, false, 16><<<gDD, 512, 0, stream>>>(
        hb_bf, nullptr, nullptr, nullptr, nullptr, nullptr, nullptr, 99,
        wFD + 3 * DF, dec_b2 + cD, x_d, x_d, nullptr, cD, 0, 0, 0, 0);

    // ---- final LN + generator + log_softmax ----
    ln_k<<<cN, 256, 0, stream>>>(x_d, dec_lnf, dec_lnf + cD, xn_bf);
    gen32_k<<<dim3(cV / 128, cN / 128), 256, 0, stream>>>(
        xn_bf, genT, gen_b, lg16, cV, cD);
    lsm_k<<<cN, 256, 0, stream>>>(lg16, (float*)d_out);
}